// Round 10
// baseline (355.435 us; speedup 1.0000x reference)
//
#include <hip/hip_runtime.h>
#include <hip/hip_bf16.h>

typedef __attribute__((ext_vector_type(8))) short short8;
typedef __attribute__((ext_vector_type(4))) short bfx4;
typedef __attribute__((ext_vector_type(4))) float floatx4;

#define SEQ     2048
#define DMODEL  768
#define DINNER  1536
#define DSTATE  128
#define NH      24
#define CONVDIM 1792
#define NPROJ   3352   // 2*DINNER + 2*DSTATE + NH
#define QCH     64     // SSD chunk length
#define NCH     (SEQ / QCH)   // 32 chunks

__device__ inline float bf2f(short s) {
    return __uint_as_float(((unsigned)(unsigned short)s) << 16);
}
__device__ inline short f2bf(float f) {
    __hip_bfloat16 h = __float2bfloat16(f);
    return *reinterpret_cast<short*>(&h);
}
__device__ inline void gl_lds16(const void* g, void* l) {
    __builtin_amdgcn_global_load_lds((const __attribute__((address_space(1))) unsigned int*)g,
                                     (__attribute__((address_space(3))) unsigned int*)l, 16, 0, 0);
}

// ---------------------------------------------------------------- fused converts (float4), 3 segments
__global__ __launch_bounds__(256) void cvt3_kernel(const float* __restrict__ s1, __hip_bfloat16* __restrict__ d1, int n1,
                                                   const float* __restrict__ s2, __hip_bfloat16* __restrict__ d2, int n2,
                                                   const float* __restrict__ s3, __hip_bfloat16* __restrict__ d3, int n3) {
    int i = blockIdx.x * 256 + threadIdx.x;
    const float* src; __hip_bfloat16* dst; int idx;
    if (i < n1)                { src = s1; dst = d1; idx = i; }
    else if (i < n1 + n2)      { src = s2; dst = d2; idx = i - n1; }
    else if (i < n1 + n2 + n3) { src = s3; dst = d3; idx = i - n1 - n2; }
    else return;
    float4 v = *(const float4*)(src + (size_t)idx * 4);
    bfx4 o = { f2bf(v.x), f2bf(v.y), f2bf(v.z), f2bf(v.w) };
    *(bfx4*)((short*)dst + (size_t)idx * 4) = o;
}

// ---------------------------------------------------------------- in_proj GEMM — EXACT R5/R7 body (measured 91us)
// Conv fusion tried (R8/R9): net-neutral — the in-loop doX overhead equals the saved conv
// launch. Reverted to the proven split form; K-loop and epilogues byte-identical to R7.
__global__ __launch_bounds__(256) void gemm_in(const __hip_bfloat16* __restrict__ Abase,
                                               const __hip_bfloat16* __restrict__ Bbase, size_t bStride,
                                               __hip_bfloat16* __restrict__ Zb,
                                               __hip_bfloat16* __restrict__ Xb,
                                               float* __restrict__ DT,
                                               float* __restrict__ LA,
                                               const float* __restrict__ dtbias,
                                               const float* __restrict__ Alog,
                                               int N, int K) {
    __shared__ short As[2][32 * 64];   // 4 KB per buf
    __shared__ short Bs[2][64 * 64];   // 8 KB per buf
    __shared__ short Tr[32][136];      // transpose staging (separate, as in R5)
    int tid = threadIdx.x;
    int w = tid >> 6, lane = tid & 63;
    int q = lane >> 4, mm = lane & 15;
    int wm = w >> 1, wn = w & 1;
    int m0 = blockIdx.x * 64, n0 = blockIdx.y * 128;
    int dir = blockIdx.z;
    const short* Ag = (const short*)Abase;
    const short* Bg = (const short*)Bbase + (size_t)dir * bStride;
    int fA = dir;

    size_t aoff; int aldso;
    {
        int ln = w * 8 + (lane >> 3);
        int s  = lane & 7;
        int c  = s ^ (ln & 7);
        int row = (c < 4) ? ln : ln + 32;
        int ch  = (c < 4) ? c : (c ^ 4);
        int ar = m0 + row;
        if (fA) { int bb = ar >> 11, tt = ar & 2047; ar = (bb << 11) + (2047 - tt); }
        aoff = (size_t)ar * K + ch * 8;
        aldso = w * 1024;
    }
    size_t boff[2];
    int bldso[2];
#pragma unroll
    for (int j = 0; j < 2; j++) {
        int widx = w * 2 + j;
        int ln = widx * 8 + (lane >> 3);
        int s  = lane & 7;
        int c  = s ^ (ln & 7);
        int row = (c < 4) ? ln : ln + 64;
        int ch  = (c < 4) ? c : (c ^ 4);
        int br = n0 + row; if (br > N - 1) br = N - 1;
        boff[j] = (size_t)br * K + ch * 8;
        bldso[j] = widx * 1024;
    }

    floatx4 acc[8];
#pragma unroll
    for (int i = 0; i < 8; i++) acc[i] = (floatx4){0.f, 0.f, 0.f, 0.f};

    int niter = K / 32;
    auto stage = [&](int buf, int k0) {
        gl_lds16(Ag + aoff + k0, (char*)&As[buf][0] + aldso);
        gl_lds16(Bg + boff[0] + k0, (char*)&Bs[buf][0] + bldso[0]);
        gl_lds16(Bg + boff[1] + k0, (char*)&Bs[buf][0] + bldso[1]);
    };
    stage(0, 0);
    int slotA = (q ^ (mm & 7) ^ (wm << 2)) * 8;
    int slotB = (q ^ (mm & 7) ^ (wn << 2)) * 8;
    for (int it = 0; it < niter; it++) {
        __syncthreads();
        if (it + 1 < niter) stage((it + 1) & 1, (it + 1) * 32);
        const short* Ab = &As[it & 1][0];
        const short* Bb = &Bs[it & 1][0];
        short8 af[2], bfr[4];
#pragma unroll
        for (int mb = 0; mb < 2; mb++)
            af[mb] = *(const short8*)&Ab[(mb * 16 + mm) * 64 + slotA];
#pragma unroll
        for (int nb = 0; nb < 4; nb++)
            bfr[nb] = *(const short8*)&Bb[(nb * 16 + mm) * 64 + slotB];
#pragma unroll
        for (int mb = 0; mb < 2; mb++)
#pragma unroll
            for (int nb = 0; nb < 4; nb++)
                acc[mb * 4 + nb] = __builtin_amdgcn_mfma_f32_16x16x32_bf16(af[mb], bfr[nb], acc[mb * 4 + nb], 0, 0, 0);
    }

    __hip_bfloat16* Zb2 = Zb + (size_t)dir * 4096 * DINNER;
    __hip_bfloat16* Xb2 = Xb + (size_t)dir * 4096 * CONVDIM;

    if (n0 + 128 <= DINNER + CONVDIM) {
        short* dstBase; int ldd, c0;
        if (n0 < DINNER) { dstBase = (short*)Zb2; ldd = DINNER; c0 = n0; }
        else             { dstBase = (short*)Xb2; ldd = CONVDIM; c0 = n0 - DINNER; }
#pragma unroll
        for (int p = 0; p < 2; p++) {
            __syncthreads();
            if (wm == p) {
#pragma unroll
                for (int mb = 0; mb < 2; mb++)
#pragma unroll
                    for (int nb = 0; nb < 4; nb++)
#pragma unroll
                        for (int r = 0; r < 4; r++)
                            Tr[mb * 16 + q * 4 + r][wn * 64 + nb * 16 + mm] =
                                f2bf(acc[mb * 4 + nb][r]);
            }
            __syncthreads();
            int row = tid >> 3, c16 = (tid & 7) * 16;
            short8 v0 = *(const short8*)&Tr[row][c16];
            short8 v1 = *(const short8*)&Tr[row][c16 + 8];
            short* dp = dstBase + (size_t)(m0 + p * 32 + row) * ldd + c0 + c16;
            *(short8*)dp = v0;
            *(short8*)(dp + 8) = v1;
        }
        return;
    }

    // dt-head block: scalar path with softplus
    float* DT2 = DT + (size_t)dir * 4096 * NH;
    float* LA2 = LA + (size_t)dir * 4096 * NH;
    const float* dtb2 = dtbias + dir * NH;
    const float* Al2  = Alog + dir * NH;
#pragma unroll
    for (int mb = 0; mb < 2; mb++) {
#pragma unroll
        for (int nb = 0; nb < 4; nb++) {
            int col = n0 + wn * 64 + nb * 16 + mm;
            if (col >= N) continue;
#pragma unroll
            for (int r = 0; r < 4; r++) {
                int rr = m0 + wm * 32 + mb * 16 + q * 4 + r;
                float v = acc[mb * 4 + nb][r];
                int hh = col - (DINNER + CONVDIM);
                float raw = v + dtb2[hh];
                float dtv = (raw > 20.f) ? raw : log1pf(__expf(raw));
                float Av  = -__expf(Al2[hh]);
                DT2[(size_t)rr * NH + hh] = dtv;
                LA2[(size_t)rr * NH + hh] = dtv * Av;
            }
        }
    }
}

// ---------------------------------------------------------------- out_proj GEMM — dir-fused, FULL-K, direct write
// zdiv=1: each block loops both dirs over K=1536 (96 K-iters), writes out directly.
// Eliminates reduce2 launch + 63MB of partial traffic (25MB partial write + 50MB reduce read
// -> 12.6MB final write). Occupancy drops to ~1.5 blocks/CU — proven non-binding on this body.
__global__ __launch_bounds__(256) void gemm_out(const __hip_bfloat16* __restrict__ Abase, size_t aStride,
                                                const __hip_bfloat16* __restrict__ Bbase, size_t bStride,
                                                float* __restrict__ C,
                                                int N, int K) {
    __shared__ short As[2][32 * 64];
    __shared__ short Bs[2][64 * 64];
    int tid = threadIdx.x;
    int w = tid >> 6, lane = tid & 63;
    int q = lane >> 4, mm = lane & 15;
    int wm = w >> 1, wn = w & 1;
    int m0 = blockIdx.x * 64, n0 = blockIdx.y * 128;
    int niter = K / 32;

    int aRow, aCh, aldso;
    {
        int ln = w * 8 + (lane >> 3);
        int s  = lane & 7;
        int c  = s ^ (ln & 7);
        aRow = (c < 4) ? ln : ln + 32;
        aCh  = (c < 4) ? c : (c ^ 4);
        aldso = w * 1024;
    }
    int bRow[2], bCh[2], bldso[2];
#pragma unroll
    for (int j = 0; j < 2; j++) {
        int widx = w * 2 + j;
        int ln = widx * 8 + (lane >> 3);
        int s  = lane & 7;
        int c  = s ^ (ln & 7);
        bRow[j] = (c < 4) ? ln : ln + 64;
        bCh[j]  = (c < 4) ? c : (c ^ 4);
        bldso[j] = widx * 1024;
    }

    floatx4 acc[8];
#pragma unroll
    for (int i = 0; i < 8; i++) acc[i] = (floatx4){0.f, 0.f, 0.f, 0.f};

    int slotA = (q ^ (mm & 7) ^ (wm << 2)) * 8;
    int slotB = (q ^ (mm & 7) ^ (wn << 2)) * 8;

    for (int d = 0; d < 2; d++) {
        const short* Ag = (const short*)Abase + (size_t)d * aStride;
        const short* Bg = (const short*)Bbase + (size_t)d * bStride;
        size_t aoff;
        {
            int ar = m0 + aRow;
            if (d) { int bb = ar >> 11, tt = ar & 2047; ar = (bb << 11) + (2047 - tt); }
            aoff = (size_t)ar * K + aCh * 8;
        }
        size_t boff[2];
#pragma unroll
        for (int j = 0; j < 2; j++) {
            int br = n0 + bRow[j]; if (br > N - 1) br = N - 1;
            boff[j] = (size_t)br * K + bCh[j] * 8;
        }
        auto stage = [&](int buf, int k0) {
            gl_lds16(Ag + aoff + k0, (char*)&As[buf][0] + aldso);
            gl_lds16(Bg + boff[0] + k0, (char*)&Bs[buf][0] + bldso[0]);
            gl_lds16(Bg + boff[1] + k0, (char*)&Bs[buf][0] + bldso[1]);
        };
        stage(0, 0);
        for (int it = 0; it < niter; it++) {
            __syncthreads();
            if (it + 1 < niter) stage((it + 1) & 1, (it + 1) * 32);
            const short* Ab = &As[it & 1][0];
            const short* Bb = &Bs[it & 1][0];
            short8 af[2], bfr[4];
#pragma unroll
            for (int mb = 0; mb < 2; mb++)
                af[mb] = *(const short8*)&Ab[(mb * 16 + mm) * 64 + slotA];
#pragma unroll
            for (int nb = 0; nb < 4; nb++)
                bfr[nb] = *(const short8*)&Bb[(nb * 16 + mm) * 64 + slotB];
#pragma unroll
            for (int mb = 0; mb < 2; mb++)
#pragma unroll
                for (int nb = 0; nb < 4; nb++)
                    acc[mb * 4 + nb] = __builtin_amdgcn_mfma_f32_16x16x32_bf16(af[mb], bfr[nb], acc[mb * 4 + nb], 0, 0, 0);
        }
    }

#pragma unroll
    for (int mb = 0; mb < 2; mb++)
#pragma unroll
        for (int nb = 0; nb < 4; nb++) {
            int col = n0 + wn * 64 + nb * 16 + mm;
#pragma unroll
            for (int r = 0; r < 4; r++) {
                int rr = m0 + wm * 32 + mb * 16 + q * 4 + r;
                C[(size_t)rr * 768 + col] = acc[mb * 4 + nb][r];
            }
        }
}

// ---------------------------------------------------------------- conv (depthwise K=4) + silu
__global__ __launch_bounds__(256) void conv_kernel(const __hip_bfloat16* __restrict__ Xb,
                                                   const float* __restrict__ conv_w,
                                                   const float* __restrict__ conv_b,
                                                   __hip_bfloat16* __restrict__ xh,
                                                   __hip_bfloat16* __restrict__ Bm,
                                                   __hip_bfloat16* __restrict__ Cm) {
    int db  = blockIdx.x >> 7;
    int dir = db >> 1;
    int t0  = (blockIdx.x & 127) * 16;
    int c8  = threadIdx.x * 8;
    if (c8 >= CONVDIM) return;

    float wk[4][8], bs[8];
#pragma unroll
    for (int j = 0; j < 8; j++) {
        bs[j] = conv_b[dir * CONVDIM + c8 + j];
#pragma unroll
        for (int k = 0; k < 4; k++) wk[k][j] = conv_w[((size_t)dir * CONVDIM + c8 + j) * 4 + k];
    }

    const short* xrow = (const short*)Xb + (size_t)db * SEQ * CONVDIM + c8;
    short8 win[4];
    const short8 zer = {0, 0, 0, 0, 0, 0, 0, 0};
#pragma unroll
    for (int k = 0; k < 3; k++) {
        int ts = t0 - 3 + k;
        win[k] = (ts >= 0) ? *(const short8*)(xrow + (size_t)ts * CONVDIM) : zer;
    }

    for (int tt = 0; tt < 16; tt++) {
        int t = t0 + tt;
        win[3] = *(const short8*)(xrow + (size_t)t * CONVDIM);
        short8 outv;
#pragma unroll
        for (int j = 0; j < 8; j++) {
            float acc = bs[j];
#pragma unroll
            for (int k = 0; k < 4; k++) acc += wk[k][j] * bf2f(win[k][j]);
            float sv = acc / (1.f + __expf(-acc));
            outv[j] = f2bf(sv);
        }
        if (c8 < DINNER)
            *(short8*)((short*)xh + (size_t)(db * SEQ + t) * DINNER + c8) = outv;
        else if (c8 < DINNER + DSTATE)
            *(short8*)((short*)Bm + (size_t)(db * SEQ + t) * DSTATE + (c8 - DINNER)) = outv;
        else
            *(short8*)((short*)Cm + (size_t)(db * SEQ + t) * DSTATE + (c8 - DINNER - DSTATE)) = outv;
        win[0] = win[1]; win[1] = win[2]; win[2] = win[3];
    }
}

// ---------------------------------------------------------------- SSD pass 1
__global__ __launch_bounds__(256) void ssd1_kernel(const __hip_bfloat16* __restrict__ XH,
                                                   const __hip_bfloat16* __restrict__ BMh,
                                                   const float* __restrict__ DT,
                                                   const float* __restrict__ LA,
                                                   short* __restrict__ SS,
                                                   float* __restrict__ CUM) {
    int blk = blockIdx.x;
    int ck = blk & 31;
    int dbh = blk >> 5;
    int hh = dbh % NH, db = dbh / NH;
    int base_row = db * SEQ + ck * QCH;

    __shared__ float cum_s[QCH], dt_s[QCH];
    __shared__ short Xt[64][72];
    __shared__ short Bt[128][72];

    int tid = threadIdx.x;
    int lane = tid & 63, w = tid >> 6;
    int q = lane >> 4, mm = lane & 15;

    if (tid < QCH) {
        float la  = LA[(size_t)(base_row + tid) * NH + hh];
        float dtv = DT[(size_t)(base_row + tid) * NH + hh];
        float cs = la;
#pragma unroll
        for (int d = 1; d < 64; d <<= 1) {
            float u = __shfl_up(cs, d);
            if (tid >= d) cs += u;
        }
        cum_s[tid] = cs;
        dt_s[tid] = dtv;
        CUM[(size_t)dbh * SEQ + ck * QCH + tid] = cs;
    }
    __syncthreads();
    float cumL = cum_s[QCH - 1];

    {
        int s2 = (tid & 31) * 2, pb = tid >> 5;
        float f0 = dt_s[s2]     * __expf(cumL - cum_s[s2]);
        float f1 = dt_s[s2 + 1] * __expf(cumL - cum_s[s2 + 1]);
        const short* r0 = (const short*)XH + (size_t)(base_row + s2) * DINNER + hh * 64 + pb * 8;
        const short* r1 = r0 + DINNER;
        short8 x0 = *(const short8*)r0;
        short8 x1 = *(const short8*)r1;
#pragma unroll
        for (int j = 0; j < 8; j++) {
            unsigned lo = (unsigned short)f2bf(f0 * bf2f(x0[j]));
            unsigned hi = (unsigned short)f2bf(f1 * bf2f(x1[j]));
            *(unsigned*)&Xt[pb * 8 + j][s2] = lo | (hi << 16);
        }
    }
    {
        int s2 = (tid & 31) * 2, nb = tid >> 5;
        const short* r0 = (const short*)BMh + (size_t)(base_row + s2) * DSTATE + nb * 16;
        const short* r1 = r0 + DSTATE;
        short8 b0a = *(const short8*)r0,  b0b = *(const short8*)(r0 + 8);
        short8 b1a = *(const short8*)r1,  b1b = *(const short8*)(r1 + 8);
#pragma unroll
        for (int j = 0; j < 8; j++) {
            *(unsigned*)&Bt[nb * 16 + j][s2] =
                (unsigned)(unsigned short)b0a[j] | ((unsigned)(unsigned short)b1a[j] << 16);
            *(unsigned*)&Bt[nb * 16 + 8 + j][s2] =
                (unsigned)(unsigned short)b0b[j] | ((unsigned)(unsigned short)b1b[j] << 16);
        }
    }
    __syncthreads();

    floatx4 acc[8];
#pragma unroll
    for (int i = 0; i < 8; i++) acc[i] = (floatx4){0.f, 0.f, 0.f, 0.f};
#pragma unroll
    for (int kk = 0; kk < 2; kk++) {
        short8 a = *(const short8*)&Xt[w * 16 + mm][kk * 32 + q * 8];
#pragma unroll
        for (int cb = 0; cb < 8; cb++) {
            short8 b = *(const short8*)&Bt[cb * 16 + mm][kk * 32 + q * 8];
            acc[cb] = __builtin_amdgcn_mfma_f32_16x16x32_bf16(a, b, acc[cb], 0, 0, 0);
        }
    }
    short* Sp = SS + (size_t)blk * 8192;
#pragma unroll
    for (int cb = 0; cb < 8; cb++)
#pragma unroll
        for (int r = 0; r < 4; r++)
            Sp[(w * 16 + q * 4 + r) * DSTATE + cb * 16 + mm] = f2bf(acc[cb][r]);
}

// ---------------------------------------------------------------- SSD pass 2: inter-chunk scan (8-way split, 128 thr)
__global__ __launch_bounds__(128) void ssd2_kernel(const short* __restrict__ SS,
                                                   const float* __restrict__ CUM,
                                                   short* __restrict__ Hprev) {
    int blk = blockIdx.x;
    int dbh = blk >> 3, part = blk & 7;
    int off = part * 1024 + threadIdx.x * 8;
    size_t base = (size_t)dbh * NCH * 8192 + off;
    float h[8];
#pragma unroll
    for (int j = 0; j < 8; j++) h[j] = 0.f;
    for (int c = 0; c < NCH; c++) {
        float W = __expf(CUM[(size_t)dbh * SEQ + c * QCH + QCH - 1]);
        size_t p = base + (size_t)c * 8192;
        short8 s = *(const short8*)(SS + p);
        short8 o;
#pragma unroll
        for (int j = 0; j < 8; j++) o[j] = f2bf(h[j]);
        *(short8*)(Hprev + p) = o;
#pragma unroll
        for (int j = 0; j < 8; j++) h[j] = fmaf(h[j], W, bf2f(s[j]));
    }
}

// ---------------------------------------------------------------- SSD pass 3
__global__ __launch_bounds__(256) void ssd3_kernel(const __hip_bfloat16* __restrict__ XH,
                                                   const __hip_bfloat16* __restrict__ BMh,
                                                   const __hip_bfloat16* __restrict__ CMh,
                                                   const float* __restrict__ DT,
                                                   const float* __restrict__ CUM,
                                                   const short* __restrict__ Hprev,
                                                   __hip_bfloat16* __restrict__ Yb) {
    int blk = blockIdx.x;
    int ck = blk & 31;
    int dbh = blk >> 5;
    int hh = dbh % NH, db = dbh / NH;
    int base_row = db * SEQ + ck * QCH;

    __shared__ float cum_s[QCH], dt_s[QCH];
    __shared__ short Ct[64][136];
    __shared__ short G[64][72];
    __shared__ short Xt[64][72];

    int tid = threadIdx.x;
    int lane = tid & 63, w = tid >> 6;
    int q = lane >> 4, mm = lane & 15;

    if (tid < QCH) {
        cum_s[tid] = CUM[(size_t)dbh * SEQ + ck * QCH + tid];
        dt_s[tid]  = DT[(size_t)(base_row + tid) * NH + hh];
    }

    const short* Cg = (const short*)CMh + (size_t)base_row * DSTATE;
    const short* Bg = (const short*)BMh + (size_t)base_row * DSTATE;
    floatx4 P[4];
#pragma unroll
    for (int i = 0; i < 4; i++) P[i] = (floatx4){0.f, 0.f, 0.f, 0.f};
#pragma unroll
    for (int kk = 0; kk < 4; kk++) {
        short8 a = *(const short8*)(Cg + (size_t)(w * 16 + mm) * DSTATE + kk * 32 + q * 8);
#pragma unroll
        for (int cb = 0; cb < 4; cb++) {
            short8 b = *(const short8*)(Bg + (size_t)(cb * 16 + mm) * DSTATE + kk * 32 + q * 8);
            P[cb] = __builtin_amdgcn_mfma_f32_16x16x32_bf16(a, b, P[cb], 0, 0, 0);
        }
    }
    __syncthreads();

    {
        int t = tid & 63, nb4 = tid >> 6;
        float wt = __expf(cum_s[t]);
        const short* src = Cg + (size_t)t * DSTATE + nb4 * 32;
#pragma unroll
        for (int u = 0; u < 2; u++) {
            short8 v = *(const short8*)(src + u * 16);
            short8 v2 = *(const short8*)(src + u * 16 + 8);
#pragma unroll
            for (int j = 0; j < 4; j++) {
                unsigned lo = (unsigned short)f2bf(wt * bf2f(v[2 * j]));
                unsigned hi = (unsigned short)f2bf(wt * bf2f(v[2 * j + 1]));
                *(unsigned*)&Ct[t][nb4 * 32 + u * 16 + 2 * j] = lo | (hi << 16);
                lo = (unsigned short)f2bf(wt * bf2f(v2[2 * j]));
                hi = (unsigned short)f2bf(wt * bf2f(v2[2 * j + 1]));
                *(unsigned*)&Ct[t][nb4 * 32 + u * 16 + 8 + 2 * j] = lo | (hi << 16);
            }
        }
    }
    {
        int s2 = (tid & 31) * 2, pb = tid >> 5;
        const short* r0 = (const short*)XH + (size_t)(base_row + s2) * DINNER + hh * 64 + pb * 8;
        const short* r1 = r0 + DINNER;
        short8 x0 = *(const short8*)r0;
        short8 x1 = *(const short8*)r1;
#pragma unroll
        for (int j = 0; j < 8; j++) {
            *(unsigned*)&Xt[pb * 8 + j][s2] =
                (unsigned)(unsigned short)x0[j] | ((unsigned)(unsigned short)x1[j] << 16);
        }
    }
#pragma unroll
    for (int cb = 0; cb < 4; cb++) {
#pragma unroll
        for (int r = 0; r < 4; r++) {
            int t = w * 16 + q * 4 + r;
            int s = cb * 16 + mm;
            float g = (s <= t) ? P[cb][r] * __expf(cum_s[t] - cum_s[s]) * dt_s[s] : 0.f;
            G[t][s] = f2bf(g);
        }
    }
    __syncthreads();

    floatx4 Y[4];
#pragma unroll
    for (int i = 0; i < 4; i++) Y[i] = (floatx4){0.f, 0.f, 0.f, 0.f};
#pragma unroll
    for (int kk = 0; kk < 2; kk++) {
        short8 a = *(const short8*)&G[w * 16 + mm][kk * 32 + q * 8];
#pragma unroll
        for (int cb = 0; cb < 4; cb++) {
            short8 b = *(const short8*)&Xt[cb * 16 + mm][kk * 32 + q * 8];
            Y[cb] = __builtin_amdgcn_mfma_f32_16x16x32_bf16(a, b, Y[cb], 0, 0, 0);
        }
    }
    const short* Hc = Hprev + (size_t)blk * 8192;
#pragma unroll
    for (int kk = 0; kk < 4; kk++) {
        short8 a = *(const short8*)&Ct[w * 16 + mm][kk * 32 + q * 8];
#pragma unroll
        for (int cb = 0; cb < 4; cb++) {
            short8 b = *(const short8*)(Hc + (size_t)(cb * 16 + mm) * DSTATE + kk * 32 + q * 8);
            Y[cb] = __builtin_amdgcn_mfma_f32_16x16x32_bf16(a, b, Y[cb], 0, 0, 0);
        }
    }
#pragma unroll
    for (int cb = 0; cb < 4; cb++)
#pragma unroll
        for (int r = 0; r < 4; r++)
            Yb[(size_t)(base_row + w * 16 + q * 4 + r) * DINNER + hh * 64 + cb * 16 + mm] =
                __float2bfloat16(Y[cb][r]);
}

// ---------------------------------------------------------------- gating + RMSNorm (192 thr x 8 ch)
__global__ __launch_bounds__(192) void gate_kernel(const __hip_bfloat16* __restrict__ Yb,
                                                   const __hip_bfloat16* __restrict__ xh,
                                                   const __hip_bfloat16* __restrict__ Zb,
                                                   const float* __restrict__ Dp,
                                                   const float* __restrict__ norm_w,
                                                   __hip_bfloat16* __restrict__ A2) {
    int row = blockIdx.x;
    int dir = row >> 12;
    int c8 = threadIdx.x * 8;
    int hd = c8 >> 6;
    const short* yr = (const short*)Yb + (size_t)row * DINNER + c8;
    const short* xr = (const short*)xh + (size_t)row * DINNER + c8;
    const short* zr = (const short*)Zb + (size_t)row * DINNER + c8;

    short8 y8 = *(const short8*)yr;
    short8 x8 = *(const short8*)xr;
    short8 z8 = *(const short8*)zr;
    float Dv = Dp[dir * NH + hd];

    float vals[8];
    float ss = 0.f;
#pragma unroll
    for (int j = 0; j < 8; j++) {
        float v = bf2f(y8[j]) + Dv * bf2f(x8[j]);
        float z = bf2f(z8[j]);
        v *= z / (1.f + __expf(-z));
        vals[j] = v;
        ss += v * v;
    }
#pragma unroll
    for (int off = 32; off; off >>= 1) ss += __shfl_down(ss, off);
    __shared__ float ls[3];
    if ((threadIdx.x & 63) == 0) ls[threadIdx.x >> 6] = ss;
    __syncthreads();
    float tot = ls[0] + ls[1] + ls[2];
    float scale = rsqrtf(tot / (float)DINNER + 1e-5f);

    const float* nw = norm_w + dir * DINNER + c8;
    short8 o;
#pragma unroll
    for (int j = 0; j < 8; j++) o[j] = f2bf(vals[j] * scale * nw[j]);
    *(short8*)((short*)A2 + (size_t)row * DINNER + c8) = o;
}

// ---------------------------------------------------------------- launch
extern "C" void kernel_launch(void* const* d_in, const int* in_sizes, int n_in,
                              void* d_out, int out_size, void* d_ws, size_t ws_size,
                              hipStream_t stream) {
    const float* x        = (const float*)d_in[0];
    const float* in_w     = (const float*)d_in[1];
    const float* conv_w   = (const float*)d_in[2];
    const float* conv_b   = (const float*)d_in[3];
    const float* dt_bias  = (const float*)d_in[4];
    const float* A_log    = (const float*)d_in[5];
    const float* Dp       = (const float*)d_in[6];
    const float* norm_w   = (const float*)d_in[7];
    const float* out_w    = (const float*)d_in[8];
    float* out = (float*)d_out;

    const size_t szW2 = (size_t)2 * DMODEL * DINNER * 2;
    const size_t szZ  = (size_t)8192 * DINNER * 2;
    const size_t szXH = (size_t)8192 * DINNER * 2;
    const size_t szBM = (size_t)8192 * DSTATE * 2;
    const size_t szCM = szBM;
    const size_t szDT = (size_t)8192 * NH * 4;
    const size_t szLA = szDT;
    const size_t szA1 = (size_t)4096 * DMODEL * 2;     // unflipped, shared by both dirs
    const size_t szW1 = (size_t)2 * NPROJ * DMODEL * 2;
    const size_t szXB = (size_t)8192 * CONVDIM * 2;
    const size_t szYb = (size_t)8192 * DINNER * 2;
    const size_t szSS = (size_t)96 * NCH * 8192 * 2;   // 50.33 MB
    const size_t szRa = szA1 + szW1 + szXB;
    size_t szR = szRa;
    if (szR < szYb) szR = szYb;
    if (szR < szSS) szR = szSS;
    const size_t szHp = szSS;
    const size_t szCU = (size_t)96 * SEQ * 4;

    char* ws = (char*)d_ws;
    size_t off = 0;
    auto alloc = [&](size_t bytes) { char* p = ws + off; off += (bytes + 255) & ~(size_t)255; return p; };

    __hip_bfloat16* W2 = (__hip_bfloat16*)alloc(szW2);
    __hip_bfloat16* Z  = (__hip_bfloat16*)alloc(szZ);
    __hip_bfloat16* XH = (__hip_bfloat16*)alloc(szXH);
    __hip_bfloat16* BM = (__hip_bfloat16*)alloc(szBM);
    __hip_bfloat16* CM = (__hip_bfloat16*)alloc(szCM);
    float* DT = (float*)alloc(szDT);
    float* LA = (float*)alloc(szLA);
    char*  R  = (char*)alloc(szR);
    __hip_bfloat16* A1  = (__hip_bfloat16*)R;
    __hip_bfloat16* W1  = (__hip_bfloat16*)(R + szA1);
    __hip_bfloat16* XBC = (__hip_bfloat16*)(R + szA1 + szW1);
    short* SS = (short*)R;
    __hip_bfloat16* Yb = (__hip_bfloat16*)R;

    short* Hp = (short*)alloc(szHp);
    float* CU = (float*)alloc(szCU);
    if (off > ws_size) return;   // clean fail instead of OOB crash

    // 1. fused converts: weights + x (A1 rows = b*SEQ+t, unflipped)
    int n1 = 2 * NPROJ * DMODEL / 4;
    int n2 = 2 * DMODEL * DINNER / 4;
    int n3 = 4096 * DMODEL / 4;
    cvt3_kernel<<<(n1 + n2 + n3 + 255) / 256, 256, 0, stream>>>(in_w, W1, n1, out_w, W2, n2, x, A1, n3);

    // 2. in_proj GEMM: exact R5/R7 kernel (91us), z = dir, dir1 flips A rows in-gather
    {
        dim3 grid(4096 / 64, (NPROJ + 127) / 128, 2);
        gemm_in<<<grid, 256, 0, stream>>>(A1,
                                          W1, (size_t)NPROJ * DMODEL,
                                          Z, XBC, DT, LA, dt_bias, A_log,
                                          NPROJ, DMODEL);
    }

    // 3. conv + silu
    conv_kernel<<<4 * 128, 256, 0, stream>>>(XBC, conv_w, conv_b, XH, BM, CM);

    // 4. SSD chunked scan (3-pass)
    ssd1_kernel<<<4 * NH * NCH, 256, 0, stream>>>(XH, BM, DT, LA, SS, CU);
    ssd2_kernel<<<96 * 8, 128, 0, stream>>>(SS, CU, Hp);
    ssd3_kernel<<<4 * NH * NCH, 256, 0, stream>>>(XH, BM, CM, DT, CU, Hp, Yb);

    // 5. gating + RMSNorm (A2 == Z, in-place)
    gate_kernel<<<2 * 4096, 192, 0, stream>>>(Yb, XH, Z, Dp, norm_w, Z);

    // 6. out_proj: dirs fused in-kernel, full K, direct write (no partials, no reduce)
    {
        dim3 grid(4096 / 64, DMODEL / 128, 1);
        gemm_out<<<grid, 256, 0, stream>>>(Z, (size_t)4096 * DINNER,
                                           W2, (size_t)DMODEL * DINNER,
                                           out,
                                           DMODEL, DINNER);
    }
}

// Round 11
// 345.264 us; speedup vs baseline: 1.0295x; 1.0295x over previous
//
#include <hip/hip_runtime.h>
#include <hip/hip_bf16.h>

typedef __attribute__((ext_vector_type(8))) short short8;
typedef __attribute__((ext_vector_type(4))) short bfx4;
typedef __attribute__((ext_vector_type(4))) float floatx4;

#define SEQ     2048
#define DMODEL  768
#define DINNER  1536
#define DSTATE  128
#define NH      24
#define CONVDIM 1792
#define NPROJ   3352   // 2*DINNER + 2*DSTATE + NH
#define QCH     64     // SSD chunk length
#define NCH     (SEQ / QCH)   // 32 chunks

__device__ inline float bf2f(short s) {
    return __uint_as_float(((unsigned)(unsigned short)s) << 16);
}
__device__ inline short f2bf(float f) {
    __hip_bfloat16 h = __float2bfloat16(f);
    return *reinterpret_cast<short*>(&h);
}
__device__ inline void gl_lds16(const void* g, void* l) {
    __builtin_amdgcn_global_load_lds((const __attribute__((address_space(1))) unsigned int*)g,
                                     (__attribute__((address_space(3))) unsigned int*)l, 16, 0, 0);
}

// ---------------------------------------------------------------- fused converts (float4), 3 segments
__global__ __launch_bounds__(256) void cvt3_kernel(const float* __restrict__ s1, __hip_bfloat16* __restrict__ d1, int n1,
                                                   const float* __restrict__ s2, __hip_bfloat16* __restrict__ d2, int n2,
                                                   const float* __restrict__ s3, __hip_bfloat16* __restrict__ d3, int n3) {
    int i = blockIdx.x * 256 + threadIdx.x;
    const float* src; __hip_bfloat16* dst; int idx;
    if (i < n1)                { src = s1; dst = d1; idx = i; }
    else if (i < n1 + n2)      { src = s2; dst = d2; idx = i - n1; }
    else if (i < n1 + n2 + n3) { src = s3; dst = d3; idx = i - n1 - n2; }
    else return;
    float4 v = *(const float4*)(src + (size_t)idx * 4);
    bfx4 o = { f2bf(v.x), f2bf(v.y), f2bf(v.z), f2bf(v.w) };
    *(bfx4*)((short*)dst + (size_t)idx * 4) = o;
}

// ---------------------------------------------------------------- in_proj GEMM — EXACT R5/R7 body (measured ~91us)
__global__ __launch_bounds__(256) void gemm_in(const __hip_bfloat16* __restrict__ Abase,
                                               const __hip_bfloat16* __restrict__ Bbase, size_t bStride,
                                               __hip_bfloat16* __restrict__ Zb,
                                               __hip_bfloat16* __restrict__ Xb,
                                               float* __restrict__ DT,
                                               float* __restrict__ LA,
                                               const float* __restrict__ dtbias,
                                               const float* __restrict__ Alog,
                                               int N, int K) {
    __shared__ short As[2][32 * 64];   // 4 KB per buf
    __shared__ short Bs[2][64 * 64];   // 8 KB per buf
    __shared__ short Tr[32][136];      // transpose staging (separate, as in R5)
    int tid = threadIdx.x;
    int w = tid >> 6, lane = tid & 63;
    int q = lane >> 4, mm = lane & 15;
    int wm = w >> 1, wn = w & 1;
    int m0 = blockIdx.x * 64, n0 = blockIdx.y * 128;
    int dir = blockIdx.z;
    const short* Ag = (const short*)Abase;
    const short* Bg = (const short*)Bbase + (size_t)dir * bStride;
    int fA = dir;

    size_t aoff; int aldso;
    {
        int ln = w * 8 + (lane >> 3);
        int s  = lane & 7;
        int c  = s ^ (ln & 7);
        int row = (c < 4) ? ln : ln + 32;
        int ch  = (c < 4) ? c : (c ^ 4);
        int ar = m0 + row;
        if (fA) { int bb = ar >> 11, tt = ar & 2047; ar = (bb << 11) + (2047 - tt); }
        aoff = (size_t)ar * K + ch * 8;
        aldso = w * 1024;
    }
    size_t boff[2];
    int bldso[2];
#pragma unroll
    for (int j = 0; j < 2; j++) {
        int widx = w * 2 + j;
        int ln = widx * 8 + (lane >> 3);
        int s  = lane & 7;
        int c  = s ^ (ln & 7);
        int row = (c < 4) ? ln : ln + 64;
        int ch  = (c < 4) ? c : (c ^ 4);
        int br = n0 + row; if (br > N - 1) br = N - 1;
        boff[j] = (size_t)br * K + ch * 8;
        bldso[j] = widx * 1024;
    }

    floatx4 acc[8];
#pragma unroll
    for (int i = 0; i < 8; i++) acc[i] = (floatx4){0.f, 0.f, 0.f, 0.f};

    int niter = K / 32;
    auto stage = [&](int buf, int k0) {
        gl_lds16(Ag + aoff + k0, (char*)&As[buf][0] + aldso);
        gl_lds16(Bg + boff[0] + k0, (char*)&Bs[buf][0] + bldso[0]);
        gl_lds16(Bg + boff[1] + k0, (char*)&Bs[buf][0] + bldso[1]);
    };
    stage(0, 0);
    int slotA = (q ^ (mm & 7) ^ (wm << 2)) * 8;
    int slotB = (q ^ (mm & 7) ^ (wn << 2)) * 8;
    for (int it = 0; it < niter; it++) {
        __syncthreads();
        if (it + 1 < niter) stage((it + 1) & 1, (it + 1) * 32);
        const short* Ab = &As[it & 1][0];
        const short* Bb = &Bs[it & 1][0];
        short8 af[2], bfr[4];
#pragma unroll
        for (int mb = 0; mb < 2; mb++)
            af[mb] = *(const short8*)&Ab[(mb * 16 + mm) * 64 + slotA];
#pragma unroll
        for (int nb = 0; nb < 4; nb++)
            bfr[nb] = *(const short8*)&Bb[(nb * 16 + mm) * 64 + slotB];
#pragma unroll
        for (int mb = 0; mb < 2; mb++)
#pragma unroll
            for (int nb = 0; nb < 4; nb++)
                acc[mb * 4 + nb] = __builtin_amdgcn_mfma_f32_16x16x32_bf16(af[mb], bfr[nb], acc[mb * 4 + nb], 0, 0, 0);
    }

    __hip_bfloat16* Zb2 = Zb + (size_t)dir * 4096 * DINNER;
    __hip_bfloat16* Xb2 = Xb + (size_t)dir * 4096 * CONVDIM;

    if (n0 + 128 <= DINNER + CONVDIM) {
        short* dstBase; int ldd, c0;
        if (n0 < DINNER) { dstBase = (short*)Zb2; ldd = DINNER; c0 = n0; }
        else             { dstBase = (short*)Xb2; ldd = CONVDIM; c0 = n0 - DINNER; }
#pragma unroll
        for (int p = 0; p < 2; p++) {
            __syncthreads();
            if (wm == p) {
#pragma unroll
                for (int mb = 0; mb < 2; mb++)
#pragma unroll
                    for (int nb = 0; nb < 4; nb++)
#pragma unroll
                        for (int r = 0; r < 4; r++)
                            Tr[mb * 16 + q * 4 + r][wn * 64 + nb * 16 + mm] =
                                f2bf(acc[mb * 4 + nb][r]);
            }
            __syncthreads();
            int row = tid >> 3, c16 = (tid & 7) * 16;
            short8 v0 = *(const short8*)&Tr[row][c16];
            short8 v1 = *(const short8*)&Tr[row][c16 + 8];
            short* dp = dstBase + (size_t)(m0 + p * 32 + row) * ldd + c0 + c16;
            *(short8*)dp = v0;
            *(short8*)(dp + 8) = v1;
        }
        return;
    }

    // dt-head block: scalar path with softplus
    float* DT2 = DT + (size_t)dir * 4096 * NH;
    float* LA2 = LA + (size_t)dir * 4096 * NH;
    const float* dtb2 = dtbias + dir * NH;
    const float* Al2  = Alog + dir * NH;
#pragma unroll
    for (int mb = 0; mb < 2; mb++) {
#pragma unroll
        for (int nb = 0; nb < 4; nb++) {
            int col = n0 + wn * 64 + nb * 16 + mm;
            if (col >= N) continue;
#pragma unroll
            for (int r = 0; r < 4; r++) {
                int rr = m0 + wm * 32 + mb * 16 + q * 4 + r;
                float v = acc[mb * 4 + nb][r];
                int hh = col - (DINNER + CONVDIM);
                float raw = v + dtb2[hh];
                float dtv = (raw > 20.f) ? raw : log1pf(__expf(raw));
                float Av  = -__expf(Al2[hh]);
                DT2[(size_t)rr * NH + hh] = dtv;
                LA2[(size_t)rr * NH + hh] = dtv * Av;
            }
        }
    }
}

// ---------------------------------------------------------------- out_proj GEMM — R7 form: z = kslice (2), dirs fused
__global__ __launch_bounds__(256) void gemm_out(const __hip_bfloat16* __restrict__ Abase, size_t aStride,
                                                const __hip_bfloat16* __restrict__ Bbase, size_t bStride,
                                                float* __restrict__ C,
                                                int N, int K, int zdiv) {
    __shared__ short As[2][32 * 64];
    __shared__ short Bs[2][64 * 64];
    int tid = threadIdx.x;
    int w = tid >> 6, lane = tid & 63;
    int q = lane >> 4, mm = lane & 15;
    int wm = w >> 1, wn = w & 1;
    int m0 = blockIdx.x * 64, n0 = blockIdx.y * 128;
    int z = blockIdx.z;
    int kl   = K / zdiv;
    int kbeg = z * kl;
    int niter = kl / 32;

    int aRow, aCh, aldso;
    {
        int ln = w * 8 + (lane >> 3);
        int s  = lane & 7;
        int c  = s ^ (ln & 7);
        aRow = (c < 4) ? ln : ln + 32;
        aCh  = (c < 4) ? c : (c ^ 4);
        aldso = w * 1024;
    }
    int bRow[2], bCh[2], bldso[2];
#pragma unroll
    for (int j = 0; j < 2; j++) {
        int widx = w * 2 + j;
        int ln = widx * 8 + (lane >> 3);
        int s  = lane & 7;
        int c  = s ^ (ln & 7);
        bRow[j] = (c < 4) ? ln : ln + 64;
        bCh[j]  = (c < 4) ? c : (c ^ 4);
        bldso[j] = widx * 1024;
    }

    floatx4 acc[8];
#pragma unroll
    for (int i = 0; i < 8; i++) acc[i] = (floatx4){0.f, 0.f, 0.f, 0.f};

    int slotA = (q ^ (mm & 7) ^ (wm << 2)) * 8;
    int slotB = (q ^ (mm & 7) ^ (wn << 2)) * 8;

    for (int d = 0; d < 2; d++) {
        const short* Ag = (const short*)Abase + (size_t)d * aStride;
        const short* Bg = (const short*)Bbase + (size_t)d * bStride;
        size_t aoff;
        {
            int ar = m0 + aRow;
            if (d) { int bb = ar >> 11, tt = ar & 2047; ar = (bb << 11) + (2047 - tt); }
            aoff = (size_t)ar * K + aCh * 8;
        }
        size_t boff[2];
#pragma unroll
        for (int j = 0; j < 2; j++) {
            int br = n0 + bRow[j]; if (br > N - 1) br = N - 1;
            boff[j] = (size_t)br * K + bCh[j] * 8;
        }
        auto stage = [&](int buf, int k0) {
            gl_lds16(Ag + aoff + kbeg + k0, (char*)&As[buf][0] + aldso);
            gl_lds16(Bg + boff[0] + kbeg + k0, (char*)&Bs[buf][0] + bldso[0]);
            gl_lds16(Bg + boff[1] + kbeg + k0, (char*)&Bs[buf][0] + bldso[1]);
        };
        stage(0, 0);
        for (int it = 0; it < niter; it++) {
            __syncthreads();
            if (it + 1 < niter) stage((it + 1) & 1, (it + 1) * 32);
            const short* Ab = &As[it & 1][0];
            const short* Bb = &Bs[it & 1][0];
            short8 af[2], bfr[4];
#pragma unroll
            for (int mb = 0; mb < 2; mb++)
                af[mb] = *(const short8*)&Ab[(mb * 16 + mm) * 64 + slotA];
#pragma unroll
            for (int nb = 0; nb < 4; nb++)
                bfr[nb] = *(const short8*)&Bb[(nb * 16 + mm) * 64 + slotB];
#pragma unroll
            for (int mb = 0; mb < 2; mb++)
#pragma unroll
                for (int nb = 0; nb < 4; nb++)
                    acc[mb * 4 + nb] = __builtin_amdgcn_mfma_f32_16x16x32_bf16(af[mb], bfr[nb], acc[mb * 4 + nb], 0, 0, 0);
        }
    }

    float* Cz = C + (size_t)z * 4096 * 768;
#pragma unroll
    for (int mb = 0; mb < 2; mb++)
#pragma unroll
        for (int nb = 0; nb < 4; nb++) {
            int col = n0 + wn * 64 + nb * 16 + mm;
#pragma unroll
            for (int r = 0; r < 4; r++) {
                int rr = m0 + wm * 32 + mb * 16 + q * 4 + r;
                Cz[(size_t)rr * 768 + col] = acc[mb * 4 + nb][r];
            }
        }
}

// ---------------------------------------------------------------- out_proj reduce: out = P0 + P1 (dirs pre-summed)
__global__ __launch_bounds__(256) void reduce2_kernel(const float* __restrict__ P, float* __restrict__ out) {
    int idx = blockIdx.x * 256 + threadIdx.x;   // 4096*192 float4 slots
    const size_t sl = (size_t)4096 * 192;
    const float4* P4 = (const float4*)P;
    float4 a = P4[idx];
    float4 b = P4[sl + idx];
    float4 o = { a.x + b.x, a.y + b.y, a.z + b.z, a.w + b.w };
    ((float4*)out)[idx] = o;
}

// ---------------------------------------------------------------- conv (depthwise K=4) + silu
__global__ __launch_bounds__(256) void conv_kernel(const __hip_bfloat16* __restrict__ Xb,
                                                   const float* __restrict__ conv_w,
                                                   const float* __restrict__ conv_b,
                                                   __hip_bfloat16* __restrict__ xh,
                                                   __hip_bfloat16* __restrict__ Bm,
                                                   __hip_bfloat16* __restrict__ Cm) {
    int db  = blockIdx.x >> 7;
    int dir = db >> 1;
    int t0  = (blockIdx.x & 127) * 16;
    int c8  = threadIdx.x * 8;
    if (c8 >= CONVDIM) return;

    float wk[4][8], bs[8];
#pragma unroll
    for (int j = 0; j < 8; j++) {
        bs[j] = conv_b[dir * CONVDIM + c8 + j];
#pragma unroll
        for (int k = 0; k < 4; k++) wk[k][j] = conv_w[((size_t)dir * CONVDIM + c8 + j) * 4 + k];
    }

    const short* xrow = (const short*)Xb + (size_t)db * SEQ * CONVDIM + c8;
    short8 win[4];
    const short8 zer = {0, 0, 0, 0, 0, 0, 0, 0};
#pragma unroll
    for (int k = 0; k < 3; k++) {
        int ts = t0 - 3 + k;
        win[k] = (ts >= 0) ? *(const short8*)(xrow + (size_t)ts * CONVDIM) : zer;
    }

    for (int tt = 0; tt < 16; tt++) {
        int t = t0 + tt;
        win[3] = *(const short8*)(xrow + (size_t)t * CONVDIM);
        short8 outv;
#pragma unroll
        for (int j = 0; j < 8; j++) {
            float acc = bs[j];
#pragma unroll
            for (int k = 0; k < 4; k++) acc += wk[k][j] * bf2f(win[k][j]);
            float sv = acc / (1.f + __expf(-acc));
            outv[j] = f2bf(sv);
        }
        if (c8 < DINNER)
            *(short8*)((short*)xh + (size_t)(db * SEQ + t) * DINNER + c8) = outv;
        else if (c8 < DINNER + DSTATE)
            *(short8*)((short*)Bm + (size_t)(db * SEQ + t) * DSTATE + (c8 - DINNER)) = outv;
        else
            *(short8*)((short*)Cm + (size_t)(db * SEQ + t) * DSTATE + (c8 - DINNER - DSTATE)) = outv;
        win[0] = win[1]; win[1] = win[2]; win[2] = win[3];
    }
}

// ---------------------------------------------------------------- SSD pass 1
__global__ __launch_bounds__(256) void ssd1_kernel(const __hip_bfloat16* __restrict__ XH,
                                                   const __hip_bfloat16* __restrict__ BMh,
                                                   const float* __restrict__ DT,
                                                   const float* __restrict__ LA,
                                                   short* __restrict__ SS,
                                                   float* __restrict__ CUM) {
    int blk = blockIdx.x;
    int ck = blk & 31;
    int dbh = blk >> 5;
    int hh = dbh % NH, db = dbh / NH;
    int base_row = db * SEQ + ck * QCH;

    __shared__ float cum_s[QCH], dt_s[QCH];
    __shared__ short Xt[64][72];
    __shared__ short Bt[128][72];

    int tid = threadIdx.x;
    int lane = tid & 63, w = tid >> 6;
    int q = lane >> 4, mm = lane & 15;

    if (tid < QCH) {
        float la  = LA[(size_t)(base_row + tid) * NH + hh];
        float dtv = DT[(size_t)(base_row + tid) * NH + hh];
        float cs = la;
#pragma unroll
        for (int d = 1; d < 64; d <<= 1) {
            float u = __shfl_up(cs, d);
            if (tid >= d) cs += u;
        }
        cum_s[tid] = cs;
        dt_s[tid] = dtv;
        CUM[(size_t)dbh * SEQ + ck * QCH + tid] = cs;
    }
    __syncthreads();
    float cumL = cum_s[QCH - 1];

    {
        int s2 = (tid & 31) * 2, pb = tid >> 5;
        float f0 = dt_s[s2]     * __expf(cumL - cum_s[s2]);
        float f1 = dt_s[s2 + 1] * __expf(cumL - cum_s[s2 + 1]);
        const short* r0 = (const short*)XH + (size_t)(base_row + s2) * DINNER + hh * 64 + pb * 8;
        const short* r1 = r0 + DINNER;
        short8 x0 = *(const short8*)r0;
        short8 x1 = *(const short8*)r1;
#pragma unroll
        for (int j = 0; j < 8; j++) {
            unsigned lo = (unsigned short)f2bf(f0 * bf2f(x0[j]));
            unsigned hi = (unsigned short)f2bf(f1 * bf2f(x1[j]));
            *(unsigned*)&Xt[pb * 8 + j][s2] = lo | (hi << 16);
        }
    }
    {
        int s2 = (tid & 31) * 2, nb = tid >> 5;
        const short* r0 = (const short*)BMh + (size_t)(base_row + s2) * DSTATE + nb * 16;
        const short* r1 = r0 + DSTATE;
        short8 b0a = *(const short8*)r0,  b0b = *(const short8*)(r0 + 8);
        short8 b1a = *(const short8*)r1,  b1b = *(const short8*)(r1 + 8);
#pragma unroll
        for (int j = 0; j < 8; j++) {
            *(unsigned*)&Bt[nb * 16 + j][s2] =
                (unsigned)(unsigned short)b0a[j] | ((unsigned)(unsigned short)b1a[j] << 16);
            *(unsigned*)&Bt[nb * 16 + 8 + j][s2] =
                (unsigned)(unsigned short)b0b[j] | ((unsigned)(unsigned short)b1b[j] << 16);
        }
    }
    __syncthreads();

    floatx4 acc[8];
#pragma unroll
    for (int i = 0; i < 8; i++) acc[i] = (floatx4){0.f, 0.f, 0.f, 0.f};
#pragma unroll
    for (int kk = 0; kk < 2; kk++) {
        short8 a = *(const short8*)&Xt[w * 16 + mm][kk * 32 + q * 8];
#pragma unroll
        for (int cb = 0; cb < 8; cb++) {
            short8 b = *(const short8*)&Bt[cb * 16 + mm][kk * 32 + q * 8];
            acc[cb] = __builtin_amdgcn_mfma_f32_16x16x32_bf16(a, b, acc[cb], 0, 0, 0);
        }
    }
    short* Sp = SS + (size_t)blk * 8192;
#pragma unroll
    for (int cb = 0; cb < 8; cb++)
#pragma unroll
        for (int r = 0; r < 4; r++)
            Sp[(w * 16 + q * 4 + r) * DSTATE + cb * 16 + mm] = f2bf(acc[cb][r]);
}

// ---------------------------------------------------------------- SSD pass 2: inter-chunk scan (R7 form)
__global__ __launch_bounds__(256) void ssd2_kernel(const short* __restrict__ SS,
                                                   const float* __restrict__ CUM,
                                                   short* __restrict__ Hprev) {
    int blk = blockIdx.x;
    int dbh = blk >> 2, part = blk & 3;
    int off = part * 2048 + threadIdx.x * 8;
    size_t base = (size_t)dbh * NCH * 8192 + off;
    float h[8];
#pragma unroll
    for (int j = 0; j < 8; j++) h[j] = 0.f;
    for (int c = 0; c < NCH; c++) {
        float W = __expf(CUM[(size_t)dbh * SEQ + c * QCH + QCH - 1]);
        size_t p = base + (size_t)c * 8192;
        short8 s = *(const short8*)(SS + p);
        short8 o;
#pragma unroll
        for (int j = 0; j < 8; j++) o[j] = f2bf(h[j]);
        *(short8*)(Hprev + p) = o;
#pragma unroll
        for (int j = 0; j < 8; j++) h[j] = fmaf(h[j], W, bf2f(s[j]));
    }
}

// ---------------------------------------------------------------- SSD pass 3 (+ fused D*xh into Yb)
__global__ __launch_bounds__(256) void ssd3_kernel(const __hip_bfloat16* __restrict__ XH,
                                                   const __hip_bfloat16* __restrict__ BMh,
                                                   const __hip_bfloat16* __restrict__ CMh,
                                                   const float* __restrict__ DT,
                                                   const float* __restrict__ CUM,
                                                   const short* __restrict__ Hprev,
                                                   const float* __restrict__ Dp,
                                                   __hip_bfloat16* __restrict__ Yb) {
    int blk = blockIdx.x;
    int ck = blk & 31;
    int dbh = blk >> 5;
    int hh = dbh % NH, db = dbh / NH;
    int base_row = db * SEQ + ck * QCH;
    float Dv = Dp[(db >> 1) * NH + hh];   // dir = db>>1

    __shared__ float cum_s[QCH], dt_s[QCH];
    __shared__ short Ct[64][136];
    __shared__ short G[64][72];
    __shared__ short Xt[64][72];

    int tid = threadIdx.x;
    int lane = tid & 63, w = tid >> 6;
    int q = lane >> 4, mm = lane & 15;

    if (tid < QCH) {
        cum_s[tid] = CUM[(size_t)dbh * SEQ + ck * QCH + tid];
        dt_s[tid]  = DT[(size_t)(base_row + tid) * NH + hh];
    }

    const short* Cg = (const short*)CMh + (size_t)base_row * DSTATE;
    const short* Bg = (const short*)BMh + (size_t)base_row * DSTATE;
    floatx4 P[4];
#pragma unroll
    for (int i = 0; i < 4; i++) P[i] = (floatx4){0.f, 0.f, 0.f, 0.f};
#pragma unroll
    for (int kk = 0; kk < 4; kk++) {
        short8 a = *(const short8*)(Cg + (size_t)(w * 16 + mm) * DSTATE + kk * 32 + q * 8);
#pragma unroll
        for (int cb = 0; cb < 4; cb++) {
            short8 b = *(const short8*)(Bg + (size_t)(cb * 16 + mm) * DSTATE + kk * 32 + q * 8);
            P[cb] = __builtin_amdgcn_mfma_f32_16x16x32_bf16(a, b, P[cb], 0, 0, 0);
        }
    }
    __syncthreads();

    {
        int t = tid & 63, nb4 = tid >> 6;
        float wt = __expf(cum_s[t]);
        const short* src = Cg + (size_t)t * DSTATE + nb4 * 32;
#pragma unroll
        for (int u = 0; u < 2; u++) {
            short8 v = *(const short8*)(src + u * 16);
            short8 v2 = *(const short8*)(src + u * 16 + 8);
#pragma unroll
            for (int j = 0; j < 4; j++) {
                unsigned lo = (unsigned short)f2bf(wt * bf2f(v[2 * j]));
                unsigned hi = (unsigned short)f2bf(wt * bf2f(v[2 * j + 1]));
                *(unsigned*)&Ct[t][nb4 * 32 + u * 16 + 2 * j] = lo | (hi << 16);
                lo = (unsigned short)f2bf(wt * bf2f(v2[2 * j]));
                hi = (unsigned short)f2bf(wt * bf2f(v2[2 * j + 1]));
                *(unsigned*)&Ct[t][nb4 * 32 + u * 16 + 8 + 2 * j] = lo | (hi << 16);
            }
        }
    }
    {
        int s2 = (tid & 31) * 2, pb = tid >> 5;
        const short* r0 = (const short*)XH + (size_t)(base_row + s2) * DINNER + hh * 64 + pb * 8;
        const short* r1 = r0 + DINNER;
        short8 x0 = *(const short8*)r0;
        short8 x1 = *(const short8*)r1;
#pragma unroll
        for (int j = 0; j < 8; j++) {
            *(unsigned*)&Xt[pb * 8 + j][s2] =
                (unsigned)(unsigned short)x0[j] | ((unsigned)(unsigned short)x1[j] << 16);
        }
    }
#pragma unroll
    for (int cb = 0; cb < 4; cb++) {
#pragma unroll
        for (int r = 0; r < 4; r++) {
            int t = w * 16 + q * 4 + r;
            int s = cb * 16 + mm;
            float g = (s <= t) ? P[cb][r] * __expf(cum_s[t] - cum_s[s]) * dt_s[s] : 0.f;
            G[t][s] = f2bf(g);
        }
    }
    __syncthreads();

    floatx4 Y[4];
#pragma unroll
    for (int i = 0; i < 4; i++) Y[i] = (floatx4){0.f, 0.f, 0.f, 0.f};
#pragma unroll
    for (int kk = 0; kk < 2; kk++) {
        short8 a = *(const short8*)&G[w * 16 + mm][kk * 32 + q * 8];
#pragma unroll
        for (int cb = 0; cb < 4; cb++) {
            short8 b = *(const short8*)&Xt[cb * 16 + mm][kk * 32 + q * 8];
            Y[cb] = __builtin_amdgcn_mfma_f32_16x16x32_bf16(a, b, Y[cb], 0, 0, 0);
        }
    }
    const short* Hc = Hprev + (size_t)blk * 8192;
#pragma unroll
    for (int kk = 0; kk < 4; kk++) {
        short8 a = *(const short8*)&Ct[w * 16 + mm][kk * 32 + q * 8];
#pragma unroll
        for (int cb = 0; cb < 4; cb++) {
            short8 b = *(const short8*)(Hc + (size_t)(cb * 16 + mm) * DSTATE + kk * 32 + q * 8);
            Y[cb] = __builtin_amdgcn_mfma_f32_16x16x32_bf16(a, b, Y[cb], 0, 0, 0);
        }
    }
    // fused D*xh: Xt[p][t] = xh[base_row+t][hh*64+p], p = cb*16+mm, t = w*16+q*4+r
#pragma unroll
    for (int cb = 0; cb < 4; cb++)
#pragma unroll
        for (int r = 0; r < 4; r++) {
            int t = w * 16 + q * 4 + r;
            float yv = Y[cb][r] + Dv * bf2f(Xt[cb * 16 + mm][t]);
            Yb[(size_t)(base_row + t) * DINNER + hh * 64 + cb * 16 + mm] = __float2bfloat16(yv);
        }
}

// ---------------------------------------------------------------- gating + RMSNorm (192 thr x 8 ch; xh pre-folded)
__global__ __launch_bounds__(192) void gate_kernel(const __hip_bfloat16* __restrict__ Yb,
                                                   const __hip_bfloat16* __restrict__ Zb,
                                                   const float* __restrict__ norm_w,
                                                   __hip_bfloat16* __restrict__ A2) {
    int row = blockIdx.x;
    int dir = row >> 12;
    int c8 = threadIdx.x * 8;
    const short* yr = (const short*)Yb + (size_t)row * DINNER + c8;
    const short* zr = (const short*)Zb + (size_t)row * DINNER + c8;

    short8 y8 = *(const short8*)yr;
    short8 z8 = *(const short8*)zr;

    float vals[8];
    float ss = 0.f;
#pragma unroll
    for (int j = 0; j < 8; j++) {
        float v = bf2f(y8[j]);
        float z = bf2f(z8[j]);
        v *= z / (1.f + __expf(-z));
        vals[j] = v;
        ss += v * v;
    }
#pragma unroll
    for (int off = 32; off; off >>= 1) ss += __shfl_down(ss, off);
    __shared__ float ls[3];
    if ((threadIdx.x & 63) == 0) ls[threadIdx.x >> 6] = ss;
    __syncthreads();
    float tot = ls[0] + ls[1] + ls[2];
    float scale = rsqrtf(tot / (float)DINNER + 1e-5f);

    const float* nw = norm_w + dir * DINNER + c8;
    short8 o;
#pragma unroll
    for (int j = 0; j < 8; j++) o[j] = f2bf(vals[j] * scale * nw[j]);
    *(short8*)((short*)A2 + (size_t)row * DINNER + c8) = o;
}

// ---------------------------------------------------------------- launch
extern "C" void kernel_launch(void* const* d_in, const int* in_sizes, int n_in,
                              void* d_out, int out_size, void* d_ws, size_t ws_size,
                              hipStream_t stream) {
    const float* x        = (const float*)d_in[0];
    const float* in_w     = (const float*)d_in[1];
    const float* conv_w   = (const float*)d_in[2];
    const float* conv_b   = (const float*)d_in[3];
    const float* dt_bias  = (const float*)d_in[4];
    const float* A_log    = (const float*)d_in[5];
    const float* Dp       = (const float*)d_in[6];
    const float* norm_w   = (const float*)d_in[7];
    const float* out_w    = (const float*)d_in[8];
    float* out = (float*)d_out;

    const size_t szW2 = (size_t)2 * DMODEL * DINNER * 2;
    const size_t szZ  = (size_t)8192 * DINNER * 2;
    const size_t szXH = (size_t)8192 * DINNER * 2;
    const size_t szBM = (size_t)8192 * DSTATE * 2;
    const size_t szCM = szBM;
    const size_t szDT = (size_t)8192 * NH * 4;
    const size_t szLA = szDT;
    const size_t szA1 = (size_t)4096 * DMODEL * 2;     // unflipped, shared by both dirs
    const size_t szW1 = (size_t)2 * NPROJ * DMODEL * 2;
    const size_t szXB = (size_t)8192 * CONVDIM * 2;
    const size_t szYb = (size_t)8192 * DINNER * 2;
    const size_t szSS = (size_t)96 * NCH * 8192 * 2;   // 50.33 MB
    const size_t szCp = (size_t)2 * 4096 * 768 * 4;    // 25.2 MB (2 dir-summed K-slices)
    const size_t szRa = szA1 + szW1 + szXB;
    size_t szR = szRa;
    if (szR < szYb) szR = szYb;
    if (szR < szSS) szR = szSS;
    if (szR < szCp) szR = szCp;
    const size_t szHp = szSS;
    const size_t szCU = (size_t)96 * SEQ * 4;

    char* ws = (char*)d_ws;
    size_t off = 0;
    auto alloc = [&](size_t bytes) { char* p = ws + off; off += (bytes + 255) & ~(size_t)255; return p; };

    __hip_bfloat16* W2 = (__hip_bfloat16*)alloc(szW2);
    __hip_bfloat16* Z  = (__hip_bfloat16*)alloc(szZ);
    __hip_bfloat16* XH = (__hip_bfloat16*)alloc(szXH);
    __hip_bfloat16* BM = (__hip_bfloat16*)alloc(szBM);
    __hip_bfloat16* CM = (__hip_bfloat16*)alloc(szCM);
    float* DT = (float*)alloc(szDT);
    float* LA = (float*)alloc(szLA);
    char*  R  = (char*)alloc(szR);
    __hip_bfloat16* A1  = (__hip_bfloat16*)R;
    __hip_bfloat16* W1  = (__hip_bfloat16*)(R + szA1);
    __hip_bfloat16* XBC = (__hip_bfloat16*)(R + szA1 + szW1);
    short* SS = (short*)R;
    __hip_bfloat16* Yb = (__hip_bfloat16*)R;
    float* Cpart = (float*)R;     // dead after gate_kernel

    short* Hp = (short*)alloc(szHp);
    float* CU = (float*)alloc(szCU);
    if (off > ws_size) return;   // clean fail instead of OOB crash

    // 1. fused converts: weights + x (A1 rows = b*SEQ+t, unflipped)
    int n1 = 2 * NPROJ * DMODEL / 4;
    int n2 = 2 * DMODEL * DINNER / 4;
    int n3 = 4096 * DMODEL / 4;
    cvt3_kernel<<<(n1 + n2 + n3 + 255) / 256, 256, 0, stream>>>(in_w, W1, n1, out_w, W2, n2, x, A1, n3);

    // 2. in_proj GEMM: exact R5/R7 kernel (~91us), z = dir, dir1 flips A rows in-gather
    {
        dim3 grid(4096 / 64, (NPROJ + 127) / 128, 2);
        gemm_in<<<grid, 256, 0, stream>>>(A1,
                                          W1, (size_t)NPROJ * DMODEL,
                                          Z, XBC, DT, LA, dt_bias, A_log,
                                          NPROJ, DMODEL);
    }

    // 3. conv + silu
    conv_kernel<<<4 * 128, 256, 0, stream>>>(XBC, conv_w, conv_b, XH, BM, CM);

    // 4. SSD chunked scan (3-pass); ssd3 folds D*xh into Yb
    ssd1_kernel<<<4 * NH * NCH, 256, 0, stream>>>(XH, BM, DT, LA, SS, CU);
    ssd2_kernel<<<4 * NH * 4, 256, 0, stream>>>(SS, CU, Hp);
    ssd3_kernel<<<4 * NH * NCH, 256, 0, stream>>>(XH, BM, CM, DT, CU, Hp, Dp, Yb);

    // 5. gating + RMSNorm (xh pre-folded; A2 == Z, in-place)
    gate_kernel<<<2 * 4096, 192, 0, stream>>>(Yb, Z, norm_w, Z);

    // 6. out_proj: R7 form — z = kslice (2), dirs fused in-kernel, then reduce2
    {
        dim3 grid(4096 / 64, DMODEL / 128, 2);
        gemm_out<<<grid, 256, 0, stream>>>(Z, (size_t)4096 * DINNER,
                                           W2, (size_t)DMODEL * DINNER,
                                           Cpart,
                                           DMODEL, DINNER, 2);
    }
    reduce2_kernel<<<4096 * 192 / 256, 256, 0, stream>>>(Cpart, out);
}

// Round 12
// 344.694 us; speedup vs baseline: 1.0312x; 1.0017x over previous
//
#include <hip/hip_runtime.h>
#include <hip/hip_bf16.h>

typedef __attribute__((ext_vector_type(8))) short short8;
typedef __attribute__((ext_vector_type(4))) short bfx4;
typedef __attribute__((ext_vector_type(4))) float floatx4;

#define SEQ     2048
#define DMODEL  768
#define DINNER  1536
#define DSTATE  128
#define NH      24
#define CONVDIM 1792
#define NPROJ   3352   // 2*DINNER + 2*DSTATE + NH
#define QCH     64     // SSD chunk length
#define NCH     (SEQ / QCH)   // 32 chunks

__device__ inline float bf2f(short s) {
    return __uint_as_float(((unsigned)(unsigned short)s) << 16);
}
__device__ inline short f2bf(float f) {
    __hip_bfloat16 h = __float2bfloat16(f);
    return *reinterpret_cast<short*>(&h);
}
__device__ inline void gl_lds16(const void* g, void* l) {
    __builtin_amdgcn_global_load_lds((const __attribute__((address_space(1))) unsigned int*)g,
                                     (__attribute__((address_space(3))) unsigned int*)l, 16, 0, 0);
}

// ---------------------------------------------------------------- fused converts (float4), 3 segments
__global__ __launch_bounds__(256) void cvt3_kernel(const float* __restrict__ s1, __hip_bfloat16* __restrict__ d1, int n1,
                                                   const float* __restrict__ s2, __hip_bfloat16* __restrict__ d2, int n2,
                                                   const float* __restrict__ s3, __hip_bfloat16* __restrict__ d3, int n3) {
    int i = blockIdx.x * 256 + threadIdx.x;
    const float* src; __hip_bfloat16* dst; int idx;
    if (i < n1)                { src = s1; dst = d1; idx = i; }
    else if (i < n1 + n2)      { src = s2; dst = d2; idx = i - n1; }
    else if (i < n1 + n2 + n3) { src = s3; dst = d3; idx = i - n1 - n2; }
    else return;
    float4 v = *(const float4*)(src + (size_t)idx * 4);
    bfx4 o = { f2bf(v.x), f2bf(v.y), f2bf(v.z), f2bf(v.w) };
    *(bfx4*)((short*)dst + (size_t)idx * 4) = o;
}

// ---------------------------------------------------------------- in_proj GEMM — EXACT R5/R7 body (measured ~91us)
__global__ __launch_bounds__(256) void gemm_in(const __hip_bfloat16* __restrict__ Abase,
                                               const __hip_bfloat16* __restrict__ Bbase, size_t bStride,
                                               __hip_bfloat16* __restrict__ Zb,
                                               __hip_bfloat16* __restrict__ Xb,
                                               float* __restrict__ DT,
                                               float* __restrict__ LA,
                                               const float* __restrict__ dtbias,
                                               const float* __restrict__ Alog,
                                               int N, int K) {
    __shared__ short As[2][32 * 64];   // 4 KB per buf
    __shared__ short Bs[2][64 * 64];   // 8 KB per buf
    __shared__ short Tr[32][136];      // transpose staging (separate, as in R5)
    int tid = threadIdx.x;
    int w = tid >> 6, lane = tid & 63;
    int q = lane >> 4, mm = lane & 15;
    int wm = w >> 1, wn = w & 1;
    int m0 = blockIdx.x * 64, n0 = blockIdx.y * 128;
    int dir = blockIdx.z;
    const short* Ag = (const short*)Abase;
    const short* Bg = (const short*)Bbase + (size_t)dir * bStride;
    int fA = dir;

    size_t aoff; int aldso;
    {
        int ln = w * 8 + (lane >> 3);
        int s  = lane & 7;
        int c  = s ^ (ln & 7);
        int row = (c < 4) ? ln : ln + 32;
        int ch  = (c < 4) ? c : (c ^ 4);
        int ar = m0 + row;
        if (fA) { int bb = ar >> 11, tt = ar & 2047; ar = (bb << 11) + (2047 - tt); }
        aoff = (size_t)ar * K + ch * 8;
        aldso = w * 1024;
    }
    size_t boff[2];
    int bldso[2];
#pragma unroll
    for (int j = 0; j < 2; j++) {
        int widx = w * 2 + j;
        int ln = widx * 8 + (lane >> 3);
        int s  = lane & 7;
        int c  = s ^ (ln & 7);
        int row = (c < 4) ? ln : ln + 64;
        int ch  = (c < 4) ? c : (c ^ 4);
        int br = n0 + row; if (br > N - 1) br = N - 1;
        boff[j] = (size_t)br * K + ch * 8;
        bldso[j] = widx * 1024;
    }

    floatx4 acc[8];
#pragma unroll
    for (int i = 0; i < 8; i++) acc[i] = (floatx4){0.f, 0.f, 0.f, 0.f};

    int niter = K / 32;
    auto stage = [&](int buf, int k0) {
        gl_lds16(Ag + aoff + k0, (char*)&As[buf][0] + aldso);
        gl_lds16(Bg + boff[0] + k0, (char*)&Bs[buf][0] + bldso[0]);
        gl_lds16(Bg + boff[1] + k0, (char*)&Bs[buf][0] + bldso[1]);
    };
    stage(0, 0);
    int slotA = (q ^ (mm & 7) ^ (wm << 2)) * 8;
    int slotB = (q ^ (mm & 7) ^ (wn << 2)) * 8;
    for (int it = 0; it < niter; it++) {
        __syncthreads();
        if (it + 1 < niter) stage((it + 1) & 1, (it + 1) * 32);
        const short* Ab = &As[it & 1][0];
        const short* Bb = &Bs[it & 1][0];
        short8 af[2], bfr[4];
#pragma unroll
        for (int mb = 0; mb < 2; mb++)
            af[mb] = *(const short8*)&Ab[(mb * 16 + mm) * 64 + slotA];
#pragma unroll
        for (int nb = 0; nb < 4; nb++)
            bfr[nb] = *(const short8*)&Bb[(nb * 16 + mm) * 64 + slotB];
#pragma unroll
        for (int mb = 0; mb < 2; mb++)
#pragma unroll
            for (int nb = 0; nb < 4; nb++)
                acc[mb * 4 + nb] = __builtin_amdgcn_mfma_f32_16x16x32_bf16(af[mb], bfr[nb], acc[mb * 4 + nb], 0, 0, 0);
    }

    __hip_bfloat16* Zb2 = Zb + (size_t)dir * 4096 * DINNER;
    __hip_bfloat16* Xb2 = Xb + (size_t)dir * 4096 * CONVDIM;

    if (n0 + 128 <= DINNER + CONVDIM) {
        short* dstBase; int ldd, c0;
        if (n0 < DINNER) { dstBase = (short*)Zb2; ldd = DINNER; c0 = n0; }
        else             { dstBase = (short*)Xb2; ldd = CONVDIM; c0 = n0 - DINNER; }
#pragma unroll
        for (int p = 0; p < 2; p++) {
            __syncthreads();
            if (wm == p) {
#pragma unroll
                for (int mb = 0; mb < 2; mb++)
#pragma unroll
                    for (int nb = 0; nb < 4; nb++)
#pragma unroll
                        for (int r = 0; r < 4; r++)
                            Tr[mb * 16 + q * 4 + r][wn * 64 + nb * 16 + mm] =
                                f2bf(acc[mb * 4 + nb][r]);
            }
            __syncthreads();
            int row = tid >> 3, c16 = (tid & 7) * 16;
            short8 v0 = *(const short8*)&Tr[row][c16];
            short8 v1 = *(const short8*)&Tr[row][c16 + 8];
            short* dp = dstBase + (size_t)(m0 + p * 32 + row) * ldd + c0 + c16;
            *(short8*)dp = v0;
            *(short8*)(dp + 8) = v1;
        }
        return;
    }

    // dt-head block: scalar path with softplus
    float* DT2 = DT + (size_t)dir * 4096 * NH;
    float* LA2 = LA + (size_t)dir * 4096 * NH;
    const float* dtb2 = dtbias + dir * NH;
    const float* Al2  = Alog + dir * NH;
#pragma unroll
    for (int mb = 0; mb < 2; mb++) {
#pragma unroll
        for (int nb = 0; nb < 4; nb++) {
            int col = n0 + wn * 64 + nb * 16 + mm;
            if (col >= N) continue;
#pragma unroll
            for (int r = 0; r < 4; r++) {
                int rr = m0 + wm * 32 + mb * 16 + q * 4 + r;
                float v = acc[mb * 4 + nb][r];
                int hh = col - (DINNER + CONVDIM);
                float raw = v + dtb2[hh];
                float dtv = (raw > 20.f) ? raw : log1pf(__expf(raw));
                float Av  = -__expf(Al2[hh]);
                DT2[(size_t)rr * NH + hh] = dtv;
                LA2[(size_t)rr * NH + hh] = dtv * Av;
            }
        }
    }
}

// ---------------------------------------------------------------- out_proj GEMM — R7 form: z = kslice (2), dirs fused
__global__ __launch_bounds__(256) void gemm_out(const __hip_bfloat16* __restrict__ Abase, size_t aStride,
                                                const __hip_bfloat16* __restrict__ Bbase, size_t bStride,
                                                float* __restrict__ C,
                                                int N, int K, int zdiv) {
    __shared__ short As[2][32 * 64];
    __shared__ short Bs[2][64 * 64];
    int tid = threadIdx.x;
    int w = tid >> 6, lane = tid & 63;
    int q = lane >> 4, mm = lane & 15;
    int wm = w >> 1, wn = w & 1;
    int m0 = blockIdx.x * 64, n0 = blockIdx.y * 128;
    int z = blockIdx.z;
    int kl   = K / zdiv;
    int kbeg = z * kl;
    int niter = kl / 32;

    int aRow, aCh, aldso;
    {
        int ln = w * 8 + (lane >> 3);
        int s  = lane & 7;
        int c  = s ^ (ln & 7);
        aRow = (c < 4) ? ln : ln + 32;
        aCh  = (c < 4) ? c : (c ^ 4);
        aldso = w * 1024;
    }
    int bRow[2], bCh[2], bldso[2];
#pragma unroll
    for (int j = 0; j < 2; j++) {
        int widx = w * 2 + j;
        int ln = widx * 8 + (lane >> 3);
        int s  = lane & 7;
        int c  = s ^ (ln & 7);
        bRow[j] = (c < 4) ? ln : ln + 64;
        bCh[j]  = (c < 4) ? c : (c ^ 4);
        bldso[j] = widx * 1024;
    }

    floatx4 acc[8];
#pragma unroll
    for (int i = 0; i < 8; i++) acc[i] = (floatx4){0.f, 0.f, 0.f, 0.f};

    int slotA = (q ^ (mm & 7) ^ (wm << 2)) * 8;
    int slotB = (q ^ (mm & 7) ^ (wn << 2)) * 8;

    for (int d = 0; d < 2; d++) {
        const short* Ag = (const short*)Abase + (size_t)d * aStride;
        const short* Bg = (const short*)Bbase + (size_t)d * bStride;
        size_t aoff;
        {
            int ar = m0 + aRow;
            if (d) { int bb = ar >> 11, tt = ar & 2047; ar = (bb << 11) + (2047 - tt); }
            aoff = (size_t)ar * K + aCh * 8;
        }
        size_t boff[2];
#pragma unroll
        for (int j = 0; j < 2; j++) {
            int br = n0 + bRow[j]; if (br > N - 1) br = N - 1;
            boff[j] = (size_t)br * K + bCh[j] * 8;
        }
        auto stage = [&](int buf, int k0) {
            gl_lds16(Ag + aoff + kbeg + k0, (char*)&As[buf][0] + aldso);
            gl_lds16(Bg + boff[0] + kbeg + k0, (char*)&Bs[buf][0] + bldso[0]);
            gl_lds16(Bg + boff[1] + kbeg + k0, (char*)&Bs[buf][0] + bldso[1]);
        };
        stage(0, 0);
        for (int it = 0; it < niter; it++) {
            __syncthreads();
            if (it + 1 < niter) stage((it + 1) & 1, (it + 1) * 32);
            const short* Ab = &As[it & 1][0];
            const short* Bb = &Bs[it & 1][0];
            short8 af[2], bfr[4];
#pragma unroll
            for (int mb = 0; mb < 2; mb++)
                af[mb] = *(const short8*)&Ab[(mb * 16 + mm) * 64 + slotA];
#pragma unroll
            for (int nb = 0; nb < 4; nb++)
                bfr[nb] = *(const short8*)&Bb[(nb * 16 + mm) * 64 + slotB];
#pragma unroll
            for (int mb = 0; mb < 2; mb++)
#pragma unroll
                for (int nb = 0; nb < 4; nb++)
                    acc[mb * 4 + nb] = __builtin_amdgcn_mfma_f32_16x16x32_bf16(af[mb], bfr[nb], acc[mb * 4 + nb], 0, 0, 0);
        }
    }

    float* Cz = C + (size_t)z * 4096 * 768;
#pragma unroll
    for (int mb = 0; mb < 2; mb++)
#pragma unroll
        for (int nb = 0; nb < 4; nb++) {
            int col = n0 + wn * 64 + nb * 16 + mm;
#pragma unroll
            for (int r = 0; r < 4; r++) {
                int rr = m0 + wm * 32 + mb * 16 + q * 4 + r;
                Cz[(size_t)rr * 768 + col] = acc[mb * 4 + nb][r];
            }
        }
}

// ---------------------------------------------------------------- out_proj reduce: out = P0 + P1 (dirs pre-summed)
__global__ __launch_bounds__(256) void reduce2_kernel(const float* __restrict__ P, float* __restrict__ out) {
    int idx = blockIdx.x * 256 + threadIdx.x;   // 4096*192 float4 slots
    const size_t sl = (size_t)4096 * 192;
    const float4* P4 = (const float4*)P;
    float4 a = P4[idx];
    float4 b = P4[sl + idx];
    float4 o = { a.x + b.x, a.y + b.y, a.z + b.z, a.w + b.w };
    ((float4*)out)[idx] = o;
}

// ---------------------------------------------------------------- conv (depthwise K=4) + silu
__global__ __launch_bounds__(256) void conv_kernel(const __hip_bfloat16* __restrict__ Xb,
                                                   const float* __restrict__ conv_w,
                                                   const float* __restrict__ conv_b,
                                                   __hip_bfloat16* __restrict__ xh,
                                                   __hip_bfloat16* __restrict__ Bm,
                                                   __hip_bfloat16* __restrict__ Cm) {
    int db  = blockIdx.x >> 7;
    int dir = db >> 1;
    int t0  = (blockIdx.x & 127) * 16;
    int c8  = threadIdx.x * 8;
    if (c8 >= CONVDIM) return;

    float wk[4][8], bs[8];
#pragma unroll
    for (int j = 0; j < 8; j++) {
        bs[j] = conv_b[dir * CONVDIM + c8 + j];
#pragma unroll
        for (int k = 0; k < 4; k++) wk[k][j] = conv_w[((size_t)dir * CONVDIM + c8 + j) * 4 + k];
    }

    const short* xrow = (const short*)Xb + (size_t)db * SEQ * CONVDIM + c8;
    short8 win[4];
    const short8 zer = {0, 0, 0, 0, 0, 0, 0, 0};
#pragma unroll
    for (int k = 0; k < 3; k++) {
        int ts = t0 - 3 + k;
        win[k] = (ts >= 0) ? *(const short8*)(xrow + (size_t)ts * CONVDIM) : zer;
    }

    for (int tt = 0; tt < 16; tt++) {
        int t = t0 + tt;
        win[3] = *(const short8*)(xrow + (size_t)t * CONVDIM);
        short8 outv;
#pragma unroll
        for (int j = 0; j < 8; j++) {
            float acc = bs[j];
#pragma unroll
            for (int k = 0; k < 4; k++) acc += wk[k][j] * bf2f(win[k][j]);
            float sv = acc / (1.f + __expf(-acc));
            outv[j] = f2bf(sv);
        }
        if (c8 < DINNER)
            *(short8*)((short*)xh + (size_t)(db * SEQ + t) * DINNER + c8) = outv;
        else if (c8 < DINNER + DSTATE)
            *(short8*)((short*)Bm + (size_t)(db * SEQ + t) * DSTATE + (c8 - DINNER)) = outv;
        else
            *(short8*)((short*)Cm + (size_t)(db * SEQ + t) * DSTATE + (c8 - DINNER - DSTATE)) = outv;
        win[0] = win[1]; win[1] = win[2]; win[2] = win[3];
    }
}

// ---------------------------------------------------------------- SSD pass 1
__global__ __launch_bounds__(256) void ssd1_kernel(const __hip_bfloat16* __restrict__ XH,
                                                   const __hip_bfloat16* __restrict__ BMh,
                                                   const float* __restrict__ DT,
                                                   const float* __restrict__ LA,
                                                   short* __restrict__ SS,
                                                   float* __restrict__ CUM) {
    int blk = blockIdx.x;
    int ck = blk & 31;
    int dbh = blk >> 5;
    int hh = dbh % NH, db = dbh / NH;
    int base_row = db * SEQ + ck * QCH;

    __shared__ float cum_s[QCH], dt_s[QCH];
    __shared__ short Xt[64][72];
    __shared__ short Bt[128][72];

    int tid = threadIdx.x;
    int lane = tid & 63, w = tid >> 6;
    int q = lane >> 4, mm = lane & 15;

    if (tid < QCH) {
        float la  = LA[(size_t)(base_row + tid) * NH + hh];
        float dtv = DT[(size_t)(base_row + tid) * NH + hh];
        float cs = la;
#pragma unroll
        for (int d = 1; d < 64; d <<= 1) {
            float u = __shfl_up(cs, d);
            if (tid >= d) cs += u;
        }
        cum_s[tid] = cs;
        dt_s[tid] = dtv;
        CUM[(size_t)dbh * SEQ + ck * QCH + tid] = cs;
    }
    __syncthreads();
    float cumL = cum_s[QCH - 1];

    {
        int s2 = (tid & 31) * 2, pb = tid >> 5;
        float f0 = dt_s[s2]     * __expf(cumL - cum_s[s2]);
        float f1 = dt_s[s2 + 1] * __expf(cumL - cum_s[s2 + 1]);
        const short* r0 = (const short*)XH + (size_t)(base_row + s2) * DINNER + hh * 64 + pb * 8;
        const short* r1 = r0 + DINNER;
        short8 x0 = *(const short8*)r0;
        short8 x1 = *(const short8*)r1;
#pragma unroll
        for (int j = 0; j < 8; j++) {
            unsigned lo = (unsigned short)f2bf(f0 * bf2f(x0[j]));
            unsigned hi = (unsigned short)f2bf(f1 * bf2f(x1[j]));
            *(unsigned*)&Xt[pb * 8 + j][s2] = lo | (hi << 16);
        }
    }
    {
        int s2 = (tid & 31) * 2, nb = tid >> 5;
        const short* r0 = (const short*)BMh + (size_t)(base_row + s2) * DSTATE + nb * 16;
        const short* r1 = r0 + DSTATE;
        short8 b0a = *(const short8*)r0,  b0b = *(const short8*)(r0 + 8);
        short8 b1a = *(const short8*)r1,  b1b = *(const short8*)(r1 + 8);
#pragma unroll
        for (int j = 0; j < 8; j++) {
            *(unsigned*)&Bt[nb * 16 + j][s2] =
                (unsigned)(unsigned short)b0a[j] | ((unsigned)(unsigned short)b1a[j] << 16);
            *(unsigned*)&Bt[nb * 16 + 8 + j][s2] =
                (unsigned)(unsigned short)b0b[j] | ((unsigned)(unsigned short)b1b[j] << 16);
        }
    }
    __syncthreads();

    floatx4 acc[8];
#pragma unroll
    for (int i = 0; i < 8; i++) acc[i] = (floatx4){0.f, 0.f, 0.f, 0.f};
#pragma unroll
    for (int kk = 0; kk < 2; kk++) {
        short8 a = *(const short8*)&Xt[w * 16 + mm][kk * 32 + q * 8];
#pragma unroll
        for (int cb = 0; cb < 8; cb++) {
            short8 b = *(const short8*)&Bt[cb * 16 + mm][kk * 32 + q * 8];
            acc[cb] = __builtin_amdgcn_mfma_f32_16x16x32_bf16(a, b, acc[cb], 0, 0, 0);
        }
    }
    short* Sp = SS + (size_t)blk * 8192;
#pragma unroll
    for (int cb = 0; cb < 8; cb++)
#pragma unroll
        for (int r = 0; r < 4; r++)
            Sp[(w * 16 + q * 4 + r) * DSTATE + cb * 16 + mm] = f2bf(acc[cb][r]);
}

// ---------------------------------------------------------------- SSD pass 2: IN-PLACE inter-chunk scan
// Reads SS[c] then overwrites it with the running prefix (state BEFORE chunk c).
// Per-thread read-then-write at the same address — no cross-thread aliasing.
// Eliminates the separate 50MB Hprev buffer; ssd3 reads the scanned SS directly.
// 8-way split (768 blocks x 128 thr, 3 blocks/CU) for latency hiding of the serial scan.
__global__ __launch_bounds__(128) void ssd2_kernel(short* __restrict__ SS,
                                                   const float* __restrict__ CUM) {
    int blk = blockIdx.x;
    int dbh = blk >> 3, part = blk & 7;
    int off = part * 1024 + threadIdx.x * 8;
    size_t base = (size_t)dbh * NCH * 8192 + off;
    float h[8];
#pragma unroll
    for (int j = 0; j < 8; j++) h[j] = 0.f;
    for (int c = 0; c < NCH; c++) {
        float W = __expf(CUM[(size_t)dbh * SEQ + c * QCH + QCH - 1]);
        size_t p = base + (size_t)c * 8192;
        short8 s = *(const short8*)(SS + p);
        short8 o;
#pragma unroll
        for (int j = 0; j < 8; j++) o[j] = f2bf(h[j]);
        *(short8*)(SS + p) = o;
#pragma unroll
        for (int j = 0; j < 8; j++) h[j] = fmaf(h[j], W, bf2f(s[j]));
    }
}

// ---------------------------------------------------------------- SSD pass 3 (+ fused D*xh into Yb)
__global__ __launch_bounds__(256) void ssd3_kernel(const __hip_bfloat16* __restrict__ XH,
                                                   const __hip_bfloat16* __restrict__ BMh,
                                                   const __hip_bfloat16* __restrict__ CMh,
                                                   const float* __restrict__ DT,
                                                   const float* __restrict__ CUM,
                                                   const short* __restrict__ Hprev,
                                                   const float* __restrict__ Dp,
                                                   __hip_bfloat16* __restrict__ Yb) {
    int blk = blockIdx.x;
    int ck = blk & 31;
    int dbh = blk >> 5;
    int hh = dbh % NH, db = dbh / NH;
    int base_row = db * SEQ + ck * QCH;
    float Dv = Dp[(db >> 1) * NH + hh];   // dir = db>>1

    __shared__ float cum_s[QCH], dt_s[QCH];
    __shared__ short Ct[64][136];
    __shared__ short G[64][72];
    __shared__ short Xt[64][72];

    int tid = threadIdx.x;
    int lane = tid & 63, w = tid >> 6;
    int q = lane >> 4, mm = lane & 15;

    if (tid < QCH) {
        cum_s[tid] = CUM[(size_t)dbh * SEQ + ck * QCH + tid];
        dt_s[tid]  = DT[(size_t)(base_row + tid) * NH + hh];
    }

    const short* Cg = (const short*)CMh + (size_t)base_row * DSTATE;
    const short* Bg = (const short*)BMh + (size_t)base_row * DSTATE;
    floatx4 P[4];
#pragma unroll
    for (int i = 0; i < 4; i++) P[i] = (floatx4){0.f, 0.f, 0.f, 0.f};
#pragma unroll
    for (int kk = 0; kk < 4; kk++) {
        short8 a = *(const short8*)(Cg + (size_t)(w * 16 + mm) * DSTATE + kk * 32 + q * 8);
#pragma unroll
        for (int cb = 0; cb < 4; cb++) {
            short8 b = *(const short8*)(Bg + (size_t)(cb * 16 + mm) * DSTATE + kk * 32 + q * 8);
            P[cb] = __builtin_amdgcn_mfma_f32_16x16x32_bf16(a, b, P[cb], 0, 0, 0);
        }
    }
    __syncthreads();

    {
        int t = tid & 63, nb4 = tid >> 6;
        float wt = __expf(cum_s[t]);
        const short* src = Cg + (size_t)t * DSTATE + nb4 * 32;
#pragma unroll
        for (int u = 0; u < 2; u++) {
            short8 v = *(const short8*)(src + u * 16);
            short8 v2 = *(const short8*)(src + u * 16 + 8);
#pragma unroll
            for (int j = 0; j < 4; j++) {
                unsigned lo = (unsigned short)f2bf(wt * bf2f(v[2 * j]));
                unsigned hi = (unsigned short)f2bf(wt * bf2f(v[2 * j + 1]));
                *(unsigned*)&Ct[t][nb4 * 32 + u * 16 + 2 * j] = lo | (hi << 16);
                lo = (unsigned short)f2bf(wt * bf2f(v2[2 * j]));
                hi = (unsigned short)f2bf(wt * bf2f(v2[2 * j + 1]));
                *(unsigned*)&Ct[t][nb4 * 32 + u * 16 + 8 + 2 * j] = lo | (hi << 16);
            }
        }
    }
    {
        int s2 = (tid & 31) * 2, pb = tid >> 5;
        const short* r0 = (const short*)XH + (size_t)(base_row + s2) * DINNER + hh * 64 + pb * 8;
        const short* r1 = r0 + DINNER;
        short8 x0 = *(const short8*)r0;
        short8 x1 = *(const short8*)r1;
#pragma unroll
        for (int j = 0; j < 8; j++) {
            *(unsigned*)&Xt[pb * 8 + j][s2] =
                (unsigned)(unsigned short)x0[j] | ((unsigned)(unsigned short)x1[j] << 16);
        }
    }
#pragma unroll
    for (int cb = 0; cb < 4; cb++) {
#pragma unroll
        for (int r = 0; r < 4; r++) {
            int t = w * 16 + q * 4 + r;
            int s = cb * 16 + mm;
            float g = (s <= t) ? P[cb][r] * __expf(cum_s[t] - cum_s[s]) * dt_s[s] : 0.f;
            G[t][s] = f2bf(g);
        }
    }
    __syncthreads();

    floatx4 Y[4];
#pragma unroll
    for (int i = 0; i < 4; i++) Y[i] = (floatx4){0.f, 0.f, 0.f, 0.f};
#pragma unroll
    for (int kk = 0; kk < 2; kk++) {
        short8 a = *(const short8*)&G[w * 16 + mm][kk * 32 + q * 8];
#pragma unroll
        for (int cb = 0; cb < 4; cb++) {
            short8 b = *(const short8*)&Xt[cb * 16 + mm][kk * 32 + q * 8];
            Y[cb] = __builtin_amdgcn_mfma_f32_16x16x32_bf16(a, b, Y[cb], 0, 0, 0);
        }
    }
    const short* Hc = Hprev + (size_t)blk * 8192;
#pragma unroll
    for (int kk = 0; kk < 4; kk++) {
        short8 a = *(const short8*)&Ct[w * 16 + mm][kk * 32 + q * 8];
#pragma unroll
        for (int cb = 0; cb < 4; cb++) {
            short8 b = *(const short8*)(Hc + (size_t)(cb * 16 + mm) * DSTATE + kk * 32 + q * 8);
            Y[cb] = __builtin_amdgcn_mfma_f32_16x16x32_bf16(a, b, Y[cb], 0, 0, 0);
        }
    }
    // fused D*xh: Xt[p][t] = xh[base_row+t][hh*64+p], p = cb*16+mm, t = w*16+q*4+r
#pragma unroll
    for (int cb = 0; cb < 4; cb++)
#pragma unroll
        for (int r = 0; r < 4; r++) {
            int t = w * 16 + q * 4 + r;
            float yv = Y[cb][r] + Dv * bf2f(Xt[cb * 16 + mm][t]);
            Yb[(size_t)(base_row + t) * DINNER + hh * 64 + cb * 16 + mm] = __float2bfloat16(yv);
        }
}

// ---------------------------------------------------------------- gating + RMSNorm (192 thr x 8 ch; xh pre-folded)
__global__ __launch_bounds__(192) void gate_kernel(const __hip_bfloat16* __restrict__ Yb,
                                                   const __hip_bfloat16* __restrict__ Zb,
                                                   const float* __restrict__ norm_w,
                                                   __hip_bfloat16* __restrict__ A2) {
    int row = blockIdx.x;
    int dir = row >> 12;
    int c8 = threadIdx.x * 8;
    const short* yr = (const short*)Yb + (size_t)row * DINNER + c8;
    const short* zr = (const short*)Zb + (size_t)row * DINNER + c8;

    short8 y8 = *(const short8*)yr;
    short8 z8 = *(const short8*)zr;

    float vals[8];
    float ss = 0.f;
#pragma unroll
    for (int j = 0; j < 8; j++) {
        float v = bf2f(y8[j]);
        float z = bf2f(z8[j]);
        v *= z / (1.f + __expf(-z));
        vals[j] = v;
        ss += v * v;
    }
#pragma unroll
    for (int off = 32; off; off >>= 1) ss += __shfl_down(ss, off);
    __shared__ float ls[3];
    if ((threadIdx.x & 63) == 0) ls[threadIdx.x >> 6] = ss;
    __syncthreads();
    float tot = ls[0] + ls[1] + ls[2];
    float scale = rsqrtf(tot / (float)DINNER + 1e-5f);

    const float* nw = norm_w + dir * DINNER + c8;
    short8 o;
#pragma unroll
    for (int j = 0; j < 8; j++) o[j] = f2bf(vals[j] * scale * nw[j]);
    *(short8*)((short*)A2 + (size_t)row * DINNER + c8) = o;
}

// ---------------------------------------------------------------- launch
extern "C" void kernel_launch(void* const* d_in, const int* in_sizes, int n_in,
                              void* d_out, int out_size, void* d_ws, size_t ws_size,
                              hipStream_t stream) {
    const float* x        = (const float*)d_in[0];
    const float* in_w     = (const float*)d_in[1];
    const float* conv_w   = (const float*)d_in[2];
    const float* conv_b   = (const float*)d_in[3];
    const float* dt_bias  = (const float*)d_in[4];
    const float* A_log    = (const float*)d_in[5];
    const float* Dp       = (const float*)d_in[6];
    const float* norm_w   = (const float*)d_in[7];
    const float* out_w    = (const float*)d_in[8];
    float* out = (float*)d_out;

    const size_t szW2 = (size_t)2 * DMODEL * DINNER * 2;
    const size_t szZ  = (size_t)8192 * DINNER * 2;
    const size_t szXH = (size_t)8192 * DINNER * 2;
    const size_t szBM = (size_t)8192 * DSTATE * 2;
    const size_t szCM = szBM;
    const size_t szDT = (size_t)8192 * NH * 4;
    const size_t szLA = szDT;
    const size_t szA1 = (size_t)4096 * DMODEL * 2;     // unflipped, shared by both dirs
    const size_t szW1 = (size_t)2 * NPROJ * DMODEL * 2;
    const size_t szXB = (size_t)8192 * CONVDIM * 2;
    const size_t szYb = (size_t)8192 * DINNER * 2;
    const size_t szSS = (size_t)96 * NCH * 8192 * 2;   // 50.33 MB (scanned in-place by ssd2)
    const size_t szCp = (size_t)2 * 4096 * 768 * 4;    // 25.2 MB (2 dir-summed K-slices)
    const size_t szRa = szA1 + szW1 + szXB;
    size_t szR = szRa;
    if (szR < szYb) szR = szYb;
    if (szR < szCp) szR = szCp;
    const size_t szCU = (size_t)96 * SEQ * 4;

    char* ws = (char*)d_ws;
    size_t off = 0;
    auto alloc = [&](size_t bytes) { char* p = ws + off; off += (bytes + 255) & ~(size_t)255; return p; };

    __hip_bfloat16* W2 = (__hip_bfloat16*)alloc(szW2);
    __hip_bfloat16* Z  = (__hip_bfloat16*)alloc(szZ);
    __hip_bfloat16* XH = (__hip_bfloat16*)alloc(szXH);
    __hip_bfloat16* BM = (__hip_bfloat16*)alloc(szBM);
    __hip_bfloat16* CM = (__hip_bfloat16*)alloc(szCM);
    float* DT = (float*)alloc(szDT);
    float* LA = (float*)alloc(szLA);
    char*  R  = (char*)alloc(szR);
    __hip_bfloat16* A1  = (__hip_bfloat16*)R;
    __hip_bfloat16* W1  = (__hip_bfloat16*)(R + szA1);
    __hip_bfloat16* XBC = (__hip_bfloat16*)(R + szA1 + szW1);
    __hip_bfloat16* Yb = (__hip_bfloat16*)R;
    float* Cpart = (float*)R;     // dead after gate_kernel

    short* SS = (short*)alloc(szSS);   // own buffer: written by ssd1, scanned in-place, read by ssd3
    float* CU = (float*)alloc(szCU);
    if (off > ws_size) return;   // clean fail instead of OOB crash

    // 1. fused converts: weights + x (A1 rows = b*SEQ+t, unflipped)
    int n1 = 2 * NPROJ * DMODEL / 4;
    int n2 = 2 * DMODEL * DINNER / 4;
    int n3 = 4096 * DMODEL / 4;
    cvt3_kernel<<<(n1 + n2 + n3 + 255) / 256, 256, 0, stream>>>(in_w, W1, n1, out_w, W2, n2, x, A1, n3);

    // 2. in_proj GEMM: exact R5/R7 kernel (~91us), z = dir, dir1 flips A rows in-gather
    {
        dim3 grid(4096 / 64, (NPROJ + 127) / 128, 2);
        gemm_in<<<grid, 256, 0, stream>>>(A1,
                                          W1, (size_t)NPROJ * DMODEL,
                                          Z, XBC, DT, LA, dt_bias, A_log,
                                          NPROJ, DMODEL);
    }

    // 3. conv + silu
    conv_kernel<<<4 * 128, 256, 0, stream>>>(XBC, conv_w, conv_b, XH, BM, CM);

    // 4. SSD chunked scan (3-pass); ssd2 scans SS in place; ssd3 folds D*xh into Yb
    ssd1_kernel<<<4 * NH * NCH, 256, 0, stream>>>(XH, BM, DT, LA, SS, CU);
    ssd2_kernel<<<96 * 8, 128, 0, stream>>>(SS, CU);
    ssd3_kernel<<<4 * NH * NCH, 256, 0, stream>>>(XH, BM, CM, DT, CU, SS, Dp, Yb);

    // 5. gating + RMSNorm (xh pre-folded; A2 == Z, in-place)
    gate_kernel<<<2 * 4096, 192, 0, stream>>>(Yb, Z, norm_w, Z);

    // 6. out_proj: R7 form — z = kslice (2), dirs fused in-kernel, then reduce2
    {
        dim3 grid(4096 / 64, DMODEL / 128, 2);
        gemm_out<<<grid, 256, 0, stream>>>(Z, (size_t)4096 * DINNER,
                                           W2, (size_t)DMODEL * DINNER,
                                           Cpart,
                                           DMODEL, DINNER, 2);
    }
    reduce2_kernel<<<4096 * 192 / 256, 256, 0, stream>>>(Cpart, out);
}

// Round 13
// 340.641 us; speedup vs baseline: 1.0434x; 1.0119x over previous
//
#include <hip/hip_runtime.h>
#include <hip/hip_bf16.h>

typedef __attribute__((ext_vector_type(8))) short short8;
typedef __attribute__((ext_vector_type(4))) short bfx4;
typedef __attribute__((ext_vector_type(4))) float floatx4;

#define SEQ     2048
#define DMODEL  768
#define DINNER  1536
#define DSTATE  128
#define NH      24
#define CONVDIM 1792
#define NPROJ   3352   // 2*DINNER + 2*DSTATE + NH
#define QCH     64     // SSD chunk length
#define NCH     (SEQ / QCH)   // 32 chunks

__device__ inline float bf2f(short s) {
    return __uint_as_float(((unsigned)(unsigned short)s) << 16);
}
__device__ inline short f2bf(float f) {
    __hip_bfloat16 h = __float2bfloat16(f);
    return *reinterpret_cast<short*>(&h);
}
__device__ inline void gl_lds16(const void* g, void* l) {
    __builtin_amdgcn_global_load_lds((const __attribute__((address_space(1))) unsigned int*)g,
                                     (__attribute__((address_space(3))) unsigned int*)l, 16, 0, 0);
}

// ---------------------------------------------------------------- fused converts (float4), 3 segments
__global__ __launch_bounds__(256) void cvt3_kernel(const float* __restrict__ s1, __hip_bfloat16* __restrict__ d1, int n1,
                                                   const float* __restrict__ s2, __hip_bfloat16* __restrict__ d2, int n2,
                                                   const float* __restrict__ s3, __hip_bfloat16* __restrict__ d3, int n3) {
    int i = blockIdx.x * 256 + threadIdx.x;
    const float* src; __hip_bfloat16* dst; int idx;
    if (i < n1)                { src = s1; dst = d1; idx = i; }
    else if (i < n1 + n2)      { src = s2; dst = d2; idx = i - n1; }
    else if (i < n1 + n2 + n3) { src = s3; dst = d3; idx = i - n1 - n2; }
    else return;
    float4 v = *(const float4*)(src + (size_t)idx * 4);
    bfx4 o = { f2bf(v.x), f2bf(v.y), f2bf(v.z), f2bf(v.w) };
    *(bfx4*)((short*)dst + (size_t)idx * 4) = o;
}

// ---------------------------------------------------------------- in_proj GEMM — EXACT R5/R7 body (measured ~91us)
__global__ __launch_bounds__(256) void gemm_in(const __hip_bfloat16* __restrict__ Abase,
                                               const __hip_bfloat16* __restrict__ Bbase, size_t bStride,
                                               __hip_bfloat16* __restrict__ Zb,
                                               __hip_bfloat16* __restrict__ Xb,
                                               float* __restrict__ DT,
                                               float* __restrict__ LA,
                                               const float* __restrict__ dtbias,
                                               const float* __restrict__ Alog,
                                               int N, int K) {
    __shared__ short As[2][32 * 64];   // 4 KB per buf
    __shared__ short Bs[2][64 * 64];   // 8 KB per buf
    __shared__ short Tr[32][136];      // transpose staging (separate, as in R5)
    int tid = threadIdx.x;
    int w = tid >> 6, lane = tid & 63;
    int q = lane >> 4, mm = lane & 15;
    int wm = w >> 1, wn = w & 1;
    int m0 = blockIdx.x * 64, n0 = blockIdx.y * 128;
    int dir = blockIdx.z;
    const short* Ag = (const short*)Abase;
    const short* Bg = (const short*)Bbase + (size_t)dir * bStride;
    int fA = dir;

    size_t aoff; int aldso;
    {
        int ln = w * 8 + (lane >> 3);
        int s  = lane & 7;
        int c  = s ^ (ln & 7);
        int row = (c < 4) ? ln : ln + 32;
        int ch  = (c < 4) ? c : (c ^ 4);
        int ar = m0 + row;
        if (fA) { int bb = ar >> 11, tt = ar & 2047; ar = (bb << 11) + (2047 - tt); }
        aoff = (size_t)ar * K + ch * 8;
        aldso = w * 1024;
    }
    size_t boff[2];
    int bldso[2];
#pragma unroll
    for (int j = 0; j < 2; j++) {
        int widx = w * 2 + j;
        int ln = widx * 8 + (lane >> 3);
        int s  = lane & 7;
        int c  = s ^ (ln & 7);
        int row = (c < 4) ? ln : ln + 64;
        int ch  = (c < 4) ? c : (c ^ 4);
        int br = n0 + row; if (br > N - 1) br = N - 1;
        boff[j] = (size_t)br * K + ch * 8;
        bldso[j] = widx * 1024;
    }

    floatx4 acc[8];
#pragma unroll
    for (int i = 0; i < 8; i++) acc[i] = (floatx4){0.f, 0.f, 0.f, 0.f};

    int niter = K / 32;
    auto stage = [&](int buf, int k0) {
        gl_lds16(Ag + aoff + k0, (char*)&As[buf][0] + aldso);
        gl_lds16(Bg + boff[0] + k0, (char*)&Bs[buf][0] + bldso[0]);
        gl_lds16(Bg + boff[1] + k0, (char*)&Bs[buf][0] + bldso[1]);
    };
    stage(0, 0);
    int slotA = (q ^ (mm & 7) ^ (wm << 2)) * 8;
    int slotB = (q ^ (mm & 7) ^ (wn << 2)) * 8;
    for (int it = 0; it < niter; it++) {
        __syncthreads();
        if (it + 1 < niter) stage((it + 1) & 1, (it + 1) * 32);
        const short* Ab = &As[it & 1][0];
        const short* Bb = &Bs[it & 1][0];
        short8 af[2], bfr[4];
#pragma unroll
        for (int mb = 0; mb < 2; mb++)
            af[mb] = *(const short8*)&Ab[(mb * 16 + mm) * 64 + slotA];
#pragma unroll
        for (int nb = 0; nb < 4; nb++)
            bfr[nb] = *(const short8*)&Bb[(nb * 16 + mm) * 64 + slotB];
#pragma unroll
        for (int mb = 0; mb < 2; mb++)
#pragma unroll
            for (int nb = 0; nb < 4; nb++)
                acc[mb * 4 + nb] = __builtin_amdgcn_mfma_f32_16x16x32_bf16(af[mb], bfr[nb], acc[mb * 4 + nb], 0, 0, 0);
    }

    __hip_bfloat16* Zb2 = Zb + (size_t)dir * 4096 * DINNER;
    __hip_bfloat16* Xb2 = Xb + (size_t)dir * 4096 * CONVDIM;

    if (n0 + 128 <= DINNER + CONVDIM) {
        short* dstBase; int ldd, c0;
        if (n0 < DINNER) { dstBase = (short*)Zb2; ldd = DINNER; c0 = n0; }
        else             { dstBase = (short*)Xb2; ldd = CONVDIM; c0 = n0 - DINNER; }
#pragma unroll
        for (int p = 0; p < 2; p++) {
            __syncthreads();
            if (wm == p) {
#pragma unroll
                for (int mb = 0; mb < 2; mb++)
#pragma unroll
                    for (int nb = 0; nb < 4; nb++)
#pragma unroll
                        for (int r = 0; r < 4; r++)
                            Tr[mb * 16 + q * 4 + r][wn * 64 + nb * 16 + mm] =
                                f2bf(acc[mb * 4 + nb][r]);
            }
            __syncthreads();
            int row = tid >> 3, c16 = (tid & 7) * 16;
            short8 v0 = *(const short8*)&Tr[row][c16];
            short8 v1 = *(const short8*)&Tr[row][c16 + 8];
            short* dp = dstBase + (size_t)(m0 + p * 32 + row) * ldd + c0 + c16;
            *(short8*)dp = v0;
            *(short8*)(dp + 8) = v1;
        }
        return;
    }

    // dt-head block: scalar path with softplus
    float* DT2 = DT + (size_t)dir * 4096 * NH;
    float* LA2 = LA + (size_t)dir * 4096 * NH;
    const float* dtb2 = dtbias + dir * NH;
    const float* Al2  = Alog + dir * NH;
#pragma unroll
    for (int mb = 0; mb < 2; mb++) {
#pragma unroll
        for (int nb = 0; nb < 4; nb++) {
            int col = n0 + wn * 64 + nb * 16 + mm;
            if (col >= N) continue;
#pragma unroll
            for (int r = 0; r < 4; r++) {
                int rr = m0 + wm * 32 + mb * 16 + q * 4 + r;
                float v = acc[mb * 4 + nb][r];
                int hh = col - (DINNER + CONVDIM);
                float raw = v + dtb2[hh];
                float dtv = (raw > 20.f) ? raw : log1pf(__expf(raw));
                float Av  = -__expf(Al2[hh]);
                DT2[(size_t)rr * NH + hh] = dtv;
                LA2[(size_t)rr * NH + hh] = dtv * Av;
            }
        }
    }
}

// ---------------------------------------------------------------- out_proj GEMM — R7 form: z = kslice (2), dirs fused
__global__ __launch_bounds__(256) void gemm_out(const __hip_bfloat16* __restrict__ Abase, size_t aStride,
                                                const __hip_bfloat16* __restrict__ Bbase, size_t bStride,
                                                float* __restrict__ C,
                                                int N, int K, int zdiv) {
    __shared__ short As[2][32 * 64];
    __shared__ short Bs[2][64 * 64];
    int tid = threadIdx.x;
    int w = tid >> 6, lane = tid & 63;
    int q = lane >> 4, mm = lane & 15;
    int wm = w >> 1, wn = w & 1;
    int m0 = blockIdx.x * 64, n0 = blockIdx.y * 128;
    int z = blockIdx.z;
    int kl   = K / zdiv;
    int kbeg = z * kl;
    int niter = kl / 32;

    int aRow, aCh, aldso;
    {
        int ln = w * 8 + (lane >> 3);
        int s  = lane & 7;
        int c  = s ^ (ln & 7);
        aRow = (c < 4) ? ln : ln + 32;
        aCh  = (c < 4) ? c : (c ^ 4);
        aldso = w * 1024;
    }
    int bRow[2], bCh[2], bldso[2];
#pragma unroll
    for (int j = 0; j < 2; j++) {
        int widx = w * 2 + j;
        int ln = widx * 8 + (lane >> 3);
        int s  = lane & 7;
        int c  = s ^ (ln & 7);
        bRow[j] = (c < 4) ? ln : ln + 64;
        bCh[j]  = (c < 4) ? c : (c ^ 4);
        bldso[j] = widx * 1024;
    }

    floatx4 acc[8];
#pragma unroll
    for (int i = 0; i < 8; i++) acc[i] = (floatx4){0.f, 0.f, 0.f, 0.f};

    int slotA = (q ^ (mm & 7) ^ (wm << 2)) * 8;
    int slotB = (q ^ (mm & 7) ^ (wn << 2)) * 8;

    for (int d = 0; d < 2; d++) {
        const short* Ag = (const short*)Abase + (size_t)d * aStride;
        const short* Bg = (const short*)Bbase + (size_t)d * bStride;
        size_t aoff;
        {
            int ar = m0 + aRow;
            if (d) { int bb = ar >> 11, tt = ar & 2047; ar = (bb << 11) + (2047 - tt); }
            aoff = (size_t)ar * K + aCh * 8;
        }
        size_t boff[2];
#pragma unroll
        for (int j = 0; j < 2; j++) {
            int br = n0 + bRow[j]; if (br > N - 1) br = N - 1;
            boff[j] = (size_t)br * K + bCh[j] * 8;
        }
        auto stage = [&](int buf, int k0) {
            gl_lds16(Ag + aoff + kbeg + k0, (char*)&As[buf][0] + aldso);
            gl_lds16(Bg + boff[0] + kbeg + k0, (char*)&Bs[buf][0] + bldso[0]);
            gl_lds16(Bg + boff[1] + kbeg + k0, (char*)&Bs[buf][0] + bldso[1]);
        };
        stage(0, 0);
        for (int it = 0; it < niter; it++) {
            __syncthreads();
            if (it + 1 < niter) stage((it + 1) & 1, (it + 1) * 32);
            const short* Ab = &As[it & 1][0];
            const short* Bb = &Bs[it & 1][0];
            short8 af[2], bfr[4];
#pragma unroll
            for (int mb = 0; mb < 2; mb++)
                af[mb] = *(const short8*)&Ab[(mb * 16 + mm) * 64 + slotA];
#pragma unroll
            for (int nb = 0; nb < 4; nb++)
                bfr[nb] = *(const short8*)&Bb[(nb * 16 + mm) * 64 + slotB];
#pragma unroll
            for (int mb = 0; mb < 2; mb++)
#pragma unroll
                for (int nb = 0; nb < 4; nb++)
                    acc[mb * 4 + nb] = __builtin_amdgcn_mfma_f32_16x16x32_bf16(af[mb], bfr[nb], acc[mb * 4 + nb], 0, 0, 0);
        }
    }

    float* Cz = C + (size_t)z * 4096 * 768;
#pragma unroll
    for (int mb = 0; mb < 2; mb++)
#pragma unroll
        for (int nb = 0; nb < 4; nb++) {
            int col = n0 + wn * 64 + nb * 16 + mm;
#pragma unroll
            for (int r = 0; r < 4; r++) {
                int rr = m0 + wm * 32 + mb * 16 + q * 4 + r;
                Cz[(size_t)rr * 768 + col] = acc[mb * 4 + nb][r];
            }
        }
}

// ---------------------------------------------------------------- out_proj reduce: out = P0 + P1 (dirs pre-summed)
__global__ __launch_bounds__(256) void reduce2_kernel(const float* __restrict__ P, float* __restrict__ out) {
    int idx = blockIdx.x * 256 + threadIdx.x;   // 4096*192 float4 slots
    const size_t sl = (size_t)4096 * 192;
    const float4* P4 = (const float4*)P;
    float4 a = P4[idx];
    float4 b = P4[sl + idx];
    float4 o = { a.x + b.x, a.y + b.y, a.z + b.z, a.w + b.w };
    ((float4*)out)[idx] = o;
}

// ---------------------------------------------------------------- conv (depthwise K=4) + silu
__global__ __launch_bounds__(256) void conv_kernel(const __hip_bfloat16* __restrict__ Xb,
                                                   const float* __restrict__ conv_w,
                                                   const float* __restrict__ conv_b,
                                                   __hip_bfloat16* __restrict__ xh,
                                                   __hip_bfloat16* __restrict__ Bm,
                                                   __hip_bfloat16* __restrict__ Cm) {
    int db  = blockIdx.x >> 7;
    int dir = db >> 1;
    int t0  = (blockIdx.x & 127) * 16;
    int c8  = threadIdx.x * 8;
    if (c8 >= CONVDIM) return;

    float wk[4][8], bs[8];
#pragma unroll
    for (int j = 0; j < 8; j++) {
        bs[j] = conv_b[dir * CONVDIM + c8 + j];
#pragma unroll
        for (int k = 0; k < 4; k++) wk[k][j] = conv_w[((size_t)dir * CONVDIM + c8 + j) * 4 + k];
    }

    const short* xrow = (const short*)Xb + (size_t)db * SEQ * CONVDIM + c8;
    short8 win[4];
    const short8 zer = {0, 0, 0, 0, 0, 0, 0, 0};
#pragma unroll
    for (int k = 0; k < 3; k++) {
        int ts = t0 - 3 + k;
        win[k] = (ts >= 0) ? *(const short8*)(xrow + (size_t)ts * CONVDIM) : zer;
    }

    for (int tt = 0; tt < 16; tt++) {
        int t = t0 + tt;
        win[3] = *(const short8*)(xrow + (size_t)t * CONVDIM);
        short8 outv;
#pragma unroll
        for (int j = 0; j < 8; j++) {
            float acc = bs[j];
#pragma unroll
            for (int k = 0; k < 4; k++) acc += wk[k][j] * bf2f(win[k][j]);
            float sv = acc / (1.f + __expf(-acc));
            outv[j] = f2bf(sv);
        }
        if (c8 < DINNER)
            *(short8*)((short*)xh + (size_t)(db * SEQ + t) * DINNER + c8) = outv;
        else if (c8 < DINNER + DSTATE)
            *(short8*)((short*)Bm + (size_t)(db * SEQ + t) * DSTATE + (c8 - DINNER)) = outv;
        else
            *(short8*)((short*)Cm + (size_t)(db * SEQ + t) * DSTATE + (c8 - DINNER - DSTATE)) = outv;
        win[0] = win[1]; win[1] = win[2]; win[2] = win[3];
    }
}

// ---------------------------------------------------------------- SSD pass 1
__global__ __launch_bounds__(256) void ssd1_kernel(const __hip_bfloat16* __restrict__ XH,
                                                   const __hip_bfloat16* __restrict__ BMh,
                                                   const float* __restrict__ DT,
                                                   const float* __restrict__ LA,
                                                   short* __restrict__ SS,
                                                   float* __restrict__ CUM) {
    int blk = blockIdx.x;
    int ck = blk & 31;
    int dbh = blk >> 5;
    int hh = dbh % NH, db = dbh / NH;
    int base_row = db * SEQ + ck * QCH;

    __shared__ float cum_s[QCH], dt_s[QCH];
    __shared__ short Xt[64][72];
    __shared__ short Bt[128][72];

    int tid = threadIdx.x;
    int lane = tid & 63, w = tid >> 6;
    int q = lane >> 4, mm = lane & 15;

    if (tid < QCH) {
        float la  = LA[(size_t)(base_row + tid) * NH + hh];
        float dtv = DT[(size_t)(base_row + tid) * NH + hh];
        float cs = la;
#pragma unroll
        for (int d = 1; d < 64; d <<= 1) {
            float u = __shfl_up(cs, d);
            if (tid >= d) cs += u;
        }
        cum_s[tid] = cs;
        dt_s[tid] = dtv;
        CUM[(size_t)dbh * SEQ + ck * QCH + tid] = cs;
    }
    __syncthreads();
    float cumL = cum_s[QCH - 1];

    {
        int s2 = (tid & 31) * 2, pb = tid >> 5;
        float f0 = dt_s[s2]     * __expf(cumL - cum_s[s2]);
        float f1 = dt_s[s2 + 1] * __expf(cumL - cum_s[s2 + 1]);
        const short* r0 = (const short*)XH + (size_t)(base_row + s2) * DINNER + hh * 64 + pb * 8;
        const short* r1 = r0 + DINNER;
        short8 x0 = *(const short8*)r0;
        short8 x1 = *(const short8*)r1;
#pragma unroll
        for (int j = 0; j < 8; j++) {
            unsigned lo = (unsigned short)f2bf(f0 * bf2f(x0[j]));
            unsigned hi = (unsigned short)f2bf(f1 * bf2f(x1[j]));
            *(unsigned*)&Xt[pb * 8 + j][s2] = lo | (hi << 16);
        }
    }
    {
        int s2 = (tid & 31) * 2, nb = tid >> 5;
        const short* r0 = (const short*)BMh + (size_t)(base_row + s2) * DSTATE + nb * 16;
        const short* r1 = r0 + DSTATE;
        short8 b0a = *(const short8*)r0,  b0b = *(const short8*)(r0 + 8);
        short8 b1a = *(const short8*)r1,  b1b = *(const short8*)(r1 + 8);
#pragma unroll
        for (int j = 0; j < 8; j++) {
            *(unsigned*)&Bt[nb * 16 + j][s2] =
                (unsigned)(unsigned short)b0a[j] | ((unsigned)(unsigned short)b1a[j] << 16);
            *(unsigned*)&Bt[nb * 16 + 8 + j][s2] =
                (unsigned)(unsigned short)b0b[j] | ((unsigned)(unsigned short)b1b[j] << 16);
        }
    }
    __syncthreads();

    floatx4 acc[8];
#pragma unroll
    for (int i = 0; i < 8; i++) acc[i] = (floatx4){0.f, 0.f, 0.f, 0.f};
#pragma unroll
    for (int kk = 0; kk < 2; kk++) {
        short8 a = *(const short8*)&Xt[w * 16 + mm][kk * 32 + q * 8];
#pragma unroll
        for (int cb = 0; cb < 8; cb++) {
            short8 b = *(const short8*)&Bt[cb * 16 + mm][kk * 32 + q * 8];
            acc[cb] = __builtin_amdgcn_mfma_f32_16x16x32_bf16(a, b, acc[cb], 0, 0, 0);
        }
    }
    short* Sp = SS + (size_t)blk * 8192;
#pragma unroll
    for (int cb = 0; cb < 8; cb++)
#pragma unroll
        for (int r = 0; r < 4; r++)
            Sp[(w * 16 + q * 4 + r) * DSTATE + cb * 16 + mm] = f2bf(acc[cb][r]);
}

// ---------------------------------------------------------------- SSD pass 2: IN-PLACE inter-chunk scan (R12 form)
__global__ __launch_bounds__(128) void ssd2_kernel(short* __restrict__ SS,
                                                   const float* __restrict__ CUM) {
    int blk = blockIdx.x;
    int dbh = blk >> 3, part = blk & 7;
    int off = part * 1024 + threadIdx.x * 8;
    size_t base = (size_t)dbh * NCH * 8192 + off;
    float h[8];
#pragma unroll
    for (int j = 0; j < 8; j++) h[j] = 0.f;
    for (int c = 0; c < NCH; c++) {
        float W = __expf(CUM[(size_t)dbh * SEQ + c * QCH + QCH - 1]);
        size_t p = base + (size_t)c * 8192;
        short8 s = *(const short8*)(SS + p);
        short8 o;
#pragma unroll
        for (int j = 0; j < 8; j++) o[j] = f2bf(h[j]);
        *(short8*)(SS + p) = o;
#pragma unroll
        for (int j = 0; j < 8; j++) h[j] = fmaf(h[j], W, bf2f(s[j]));
    }
}

// ---------------------------------------------------------------- SSD pass 3 (+ fused D*xh; single Cg read via LDS)
// Cg is staged RAW into Ct once (coalesced 64B/thread); the C.B^T matmul reads A-fragments
// from Ct (same LDS pattern as the existing Y-loop — known conflict-clean); then Ct is
// weighted IN PLACE by exp(cum[t]) behind a barrier. Removes the second 16KB global read
// of Cg per block (~50MB across the dispatch) at zero LDS cost (+1 barrier).
__global__ __launch_bounds__(256) void ssd3_kernel(const __hip_bfloat16* __restrict__ XH,
                                                   const __hip_bfloat16* __restrict__ BMh,
                                                   const __hip_bfloat16* __restrict__ CMh,
                                                   const float* __restrict__ DT,
                                                   const float* __restrict__ CUM,
                                                   const short* __restrict__ Hprev,
                                                   const float* __restrict__ Dp,
                                                   __hip_bfloat16* __restrict__ Yb) {
    int blk = blockIdx.x;
    int ck = blk & 31;
    int dbh = blk >> 5;
    int hh = dbh % NH, db = dbh / NH;
    int base_row = db * SEQ + ck * QCH;
    float Dv = Dp[(db >> 1) * NH + hh];   // dir = db>>1

    __shared__ float cum_s[QCH], dt_s[QCH];
    __shared__ short Ct[64][136];
    __shared__ short G[64][72];
    __shared__ short Xt[64][72];

    int tid = threadIdx.x;
    int lane = tid & 63, w = tid >> 6;
    int q = lane >> 4, mm = lane & 15;

    if (tid < QCH) {
        cum_s[tid] = CUM[(size_t)dbh * SEQ + ck * QCH + tid];
        dt_s[tid]  = DT[(size_t)(base_row + tid) * NH + hh];
    }

    const short* Cg = (const short*)CMh + (size_t)base_row * DSTATE;
    const short* Bg = (const short*)BMh + (size_t)base_row * DSTATE;

    // stage Cg RAW into Ct: thread (t = tid&63, nb4 = tid>>6) covers cols nb4*32..+31
    {
        int t = tid & 63, nb4 = tid >> 6;
        const short* src = Cg + (size_t)t * DSTATE + nb4 * 32;
#pragma unroll
        for (int u = 0; u < 2; u++) {
            *(short8*)&Ct[t][nb4 * 32 + u * 16]     = *(const short8*)(src + u * 16);
            *(short8*)&Ct[t][nb4 * 32 + u * 16 + 8] = *(const short8*)(src + u * 16 + 8);
        }
    }
    // Xt staging (independent of Ct)
    {
        int s2 = (tid & 31) * 2, pb = tid >> 5;
        const short* r0 = (const short*)XH + (size_t)(base_row + s2) * DINNER + hh * 64 + pb * 8;
        const short* r1 = r0 + DINNER;
        short8 x0 = *(const short8*)r0;
        short8 x1 = *(const short8*)r1;
#pragma unroll
        for (int j = 0; j < 8; j++) {
            *(unsigned*)&Xt[pb * 8 + j][s2] =
                (unsigned)(unsigned short)x0[j] | ((unsigned)(unsigned short)x1[j] << 16);
        }
    }
    __syncthreads();

    // P = C . B^T : A-fragments from Ct (LDS), B from global
    floatx4 P[4];
#pragma unroll
    for (int i = 0; i < 4; i++) P[i] = (floatx4){0.f, 0.f, 0.f, 0.f};
#pragma unroll
    for (int kk = 0; kk < 4; kk++) {
        short8 a = *(const short8*)&Ct[w * 16 + mm][kk * 32 + q * 8];
#pragma unroll
        for (int cb = 0; cb < 4; cb++) {
            short8 b = *(const short8*)(Bg + (size_t)(cb * 16 + mm) * DSTATE + kk * 32 + q * 8);
            P[cb] = __builtin_amdgcn_mfma_f32_16x16x32_bf16(a, b, P[cb], 0, 0, 0);
        }
    }
    __syncthreads();   // all Ct reads for P done; safe to overwrite

    // weight Ct in place: Ct[t][s] *= exp(cum[t]); G from P
    {
        int t = tid & 63, nb4 = tid >> 6;
        float wt = __expf(cum_s[t]);
#pragma unroll
        for (int u = 0; u < 4; u++) {
            short8 v = *(const short8*)&Ct[t][nb4 * 32 + u * 8];
            short8 o;
#pragma unroll
            for (int j = 0; j < 8; j++) o[j] = f2bf(wt * bf2f(v[j]));
            *(short8*)&Ct[t][nb4 * 32 + u * 8] = o;
        }
    }
#pragma unroll
    for (int cb = 0; cb < 4; cb++) {
#pragma unroll
        for (int r = 0; r < 4; r++) {
            int t = w * 16 + q * 4 + r;
            int s = cb * 16 + mm;
            float g = (s <= t) ? P[cb][r] * __expf(cum_s[t] - cum_s[s]) * dt_s[s] : 0.f;
            G[t][s] = f2bf(g);
        }
    }
    __syncthreads();

    floatx4 Y[4];
#pragma unroll
    for (int i = 0; i < 4; i++) Y[i] = (floatx4){0.f, 0.f, 0.f, 0.f};
#pragma unroll
    for (int kk = 0; kk < 2; kk++) {
        short8 a = *(const short8*)&G[w * 16 + mm][kk * 32 + q * 8];
#pragma unroll
        for (int cb = 0; cb < 4; cb++) {
            short8 b = *(const short8*)&Xt[cb * 16 + mm][kk * 32 + q * 8];
            Y[cb] = __builtin_amdgcn_mfma_f32_16x16x32_bf16(a, b, Y[cb], 0, 0, 0);
        }
    }
    const short* Hc = Hprev + (size_t)blk * 8192;
#pragma unroll
    for (int kk = 0; kk < 4; kk++) {
        short8 a = *(const short8*)&Ct[w * 16 + mm][kk * 32 + q * 8];
#pragma unroll
        for (int cb = 0; cb < 4; cb++) {
            short8 b = *(const short8*)(Hc + (size_t)(cb * 16 + mm) * DSTATE + kk * 32 + q * 8);
            Y[cb] = __builtin_amdgcn_mfma_f32_16x16x32_bf16(a, b, Y[cb], 0, 0, 0);
        }
    }
    // fused D*xh: Xt[p][t] = xh[base_row+t][hh*64+p], p = cb*16+mm, t = w*16+q*4+r
#pragma unroll
    for (int cb = 0; cb < 4; cb++)
#pragma unroll
        for (int r = 0; r < 4; r++) {
            int t = w * 16 + q * 4 + r;
            float yv = Y[cb][r] + Dv * bf2f(Xt[cb * 16 + mm][t]);
            Yb[(size_t)(base_row + t) * DINNER + hh * 64 + cb * 16 + mm] = __float2bfloat16(yv);
        }
}

// ---------------------------------------------------------------- gating + RMSNorm (192 thr x 8 ch; xh pre-folded)
__global__ __launch_bounds__(192) void gate_kernel(const __hip_bfloat16* __restrict__ Yb,
                                                   const __hip_bfloat16* __restrict__ Zb,
                                                   const float* __restrict__ norm_w,
                                                   __hip_bfloat16* __restrict__ A2) {
    int row = blockIdx.x;
    int dir = row >> 12;
    int c8 = threadIdx.x * 8;
    const short* yr = (const short*)Yb + (size_t)row * DINNER + c8;
    const short* zr = (const short*)Zb + (size_t)row * DINNER + c8;

    short8 y8 = *(const short8*)yr;
    short8 z8 = *(const short8*)zr;

    float vals[8];
    float ss = 0.f;
#pragma unroll
    for (int j = 0; j < 8; j++) {
        float v = bf2f(y8[j]);
        float z = bf2f(z8[j]);
        v *= z / (1.f + __expf(-z));
        vals[j] = v;
        ss += v * v;
    }
#pragma unroll
    for (int off = 32; off; off >>= 1) ss += __shfl_down(ss, off);
    __shared__ float ls[3];
    if ((threadIdx.x & 63) == 0) ls[threadIdx.x >> 6] = ss;
    __syncthreads();
    float tot = ls[0] + ls[1] + ls[2];
    float scale = rsqrtf(tot / (float)DINNER + 1e-5f);

    const float* nw = norm_w + dir * DINNER + c8;
    short8 o;
#pragma unroll
    for (int j = 0; j < 8; j++) o[j] = f2bf(vals[j] * scale * nw[j]);
    *(short8*)((short*)A2 + (size_t)row * DINNER + c8) = o;
}

// ---------------------------------------------------------------- launch
extern "C" void kernel_launch(void* const* d_in, const int* in_sizes, int n_in,
                              void* d_out, int out_size, void* d_ws, size_t ws_size,
                              hipStream_t stream) {
    const float* x        = (const float*)d_in[0];
    const float* in_w     = (const float*)d_in[1];
    const float* conv_w   = (const float*)d_in[2];
    const float* conv_b   = (const float*)d_in[3];
    const float* dt_bias  = (const float*)d_in[4];
    const float* A_log    = (const float*)d_in[5];
    const float* Dp       = (const float*)d_in[6];
    const float* norm_w   = (const float*)d_in[7];
    const float* out_w    = (const float*)d_in[8];
    float* out = (float*)d_out;

    const size_t szW2 = (size_t)2 * DMODEL * DINNER * 2;
    const size_t szZ  = (size_t)8192 * DINNER * 2;
    const size_t szXH = (size_t)8192 * DINNER * 2;
    const size_t szBM = (size_t)8192 * DSTATE * 2;
    const size_t szCM = szBM;
    const size_t szDT = (size_t)8192 * NH * 4;
    const size_t szLA = szDT;
    const size_t szA1 = (size_t)4096 * DMODEL * 2;     // unflipped, shared by both dirs
    const size_t szW1 = (size_t)2 * NPROJ * DMODEL * 2;
    const size_t szXB = (size_t)8192 * CONVDIM * 2;
    const size_t szYb = (size_t)8192 * DINNER * 2;
    const size_t szSS = (size_t)96 * NCH * 8192 * 2;   // 50.33 MB (scanned in-place by ssd2)
    const size_t szCp = (size_t)2 * 4096 * 768 * 4;    // 25.2 MB (2 dir-summed K-slices)
    const size_t szRa = szA1 + szW1 + szXB;
    size_t szR = szRa;
    if (szR < szYb) szR = szYb;
    if (szR < szCp) szR = szCp;
    const size_t szCU = (size_t)96 * SEQ * 4;

    char* ws = (char*)d_ws;
    size_t off = 0;
    auto alloc = [&](size_t bytes) { char* p = ws + off; off += (bytes + 255) & ~(size_t)255; return p; };

    __hip_bfloat16* W2 = (__hip_bfloat16*)alloc(szW2);
    __hip_bfloat16* Z  = (__hip_bfloat16*)alloc(szZ);
    __hip_bfloat16* XH = (__hip_bfloat16*)alloc(szXH);
    __hip_bfloat16* BM = (__hip_bfloat16*)alloc(szBM);
    __hip_bfloat16* CM = (__hip_bfloat16*)alloc(szCM);
    float* DT = (float*)alloc(szDT);
    float* LA = (float*)alloc(szLA);
    char*  R  = (char*)alloc(szR);
    __hip_bfloat16* A1  = (__hip_bfloat16*)R;
    __hip_bfloat16* W1  = (__hip_bfloat16*)(R + szA1);
    __hip_bfloat16* XBC = (__hip_bfloat16*)(R + szA1 + szW1);
    __hip_bfloat16* Yb = (__hip_bfloat16*)R;
    float* Cpart = (float*)R;     // dead after gate_kernel

    short* SS = (short*)alloc(szSS);   // own buffer: written by ssd1, scanned in-place, read by ssd3
    float* CU = (float*)alloc(szCU);
    if (off > ws_size) return;   // clean fail instead of OOB crash

    // 1. fused converts: weights + x (A1 rows = b*SEQ+t, unflipped)
    int n1 = 2 * NPROJ * DMODEL / 4;
    int n2 = 2 * DMODEL * DINNER / 4;
    int n3 = 4096 * DMODEL / 4;
    cvt3_kernel<<<(n1 + n2 + n3 + 255) / 256, 256, 0, stream>>>(in_w, W1, n1, out_w, W2, n2, x, A1, n3);

    // 2. in_proj GEMM: exact R5/R7 kernel (~91us), z = dir, dir1 flips A rows in-gather
    {
        dim3 grid(4096 / 64, (NPROJ + 127) / 128, 2);
        gemm_in<<<grid, 256, 0, stream>>>(A1,
                                          W1, (size_t)NPROJ * DMODEL,
                                          Z, XBC, DT, LA, dt_bias, A_log,
                                          NPROJ, DMODEL);
    }

    // 3. conv + silu
    conv_kernel<<<4 * 128, 256, 0, stream>>>(XBC, conv_w, conv_b, XH, BM, CM);

    // 4. SSD chunked scan (3-pass); ssd2 scans SS in place; ssd3 single-Cg-read + D*xh fold
    ssd1_kernel<<<4 * NH * NCH, 256, 0, stream>>>(XH, BM, DT, LA, SS, CU);
    ssd2_kernel<<<96 * 8, 128, 0, stream>>>(SS, CU);
    ssd3_kernel<<<4 * NH * NCH, 256, 0, stream>>>(XH, BM, CM, DT, CU, SS, Dp, Yb);

    // 5. gating + RMSNorm (xh pre-folded; A2 == Z, in-place)
    gate_kernel<<<2 * 4096, 192, 0, stream>>>(Yb, Z, norm_w, Z);

    // 6. out_proj: R7 form — z = kslice (2), dirs fused in-kernel, then reduce2
    {
        dim3 grid(4096 / 64, DMODEL / 128, 2);
        gemm_out<<<grid, 256, 0, stream>>>(Z, (size_t)4096 * DINNER,
                                           W2, (size_t)DMODEL * DINNER,
                                           Cpart,
                                           DMODEL, DINNER, 2);
    }
    reduce2_kernel<<<4096 * 192 / 256, 256, 0, stream>>>(Cpart, out);
}

// Round 14
// 339.720 us; speedup vs baseline: 1.0463x; 1.0027x over previous
//
#include <hip/hip_runtime.h>
#include <hip/hip_bf16.h>

typedef __attribute__((ext_vector_type(8))) short short8;
typedef __attribute__((ext_vector_type(4))) short bfx4;
typedef __attribute__((ext_vector_type(4))) float floatx4;

#define SEQ     2048
#define DMODEL  768
#define DINNER  1536
#define DSTATE  128
#define NH      24
#define CONVDIM 1792
#define NPROJ   3352   // 2*DINNER + 2*DSTATE + NH
#define QCH     64     // SSD chunk length
#define NCH     (SEQ / QCH)   // 32 chunks

__device__ inline float bf2f(short s) {
    return __uint_as_float(((unsigned)(unsigned short)s) << 16);
}
__device__ inline short f2bf(float f) {
    __hip_bfloat16 h = __float2bfloat16(f);
    return *reinterpret_cast<short*>(&h);
}
__device__ inline void gl_lds16(const void* g, void* l) {
    __builtin_amdgcn_global_load_lds((const __attribute__((address_space(1))) unsigned int*)g,
                                     (__attribute__((address_space(3))) unsigned int*)l, 16, 0, 0);
}

// ---------------------------------------------------------------- fused converts (float4), 3 segments
__global__ __launch_bounds__(256) void cvt3_kernel(const float* __restrict__ s1, __hip_bfloat16* __restrict__ d1, int n1,
                                                   const float* __restrict__ s2, __hip_bfloat16* __restrict__ d2, int n2,
                                                   const float* __restrict__ s3, __hip_bfloat16* __restrict__ d3, int n3) {
    int i = blockIdx.x * 256 + threadIdx.x;
    const float* src; __hip_bfloat16* dst; int idx;
    if (i < n1)                { src = s1; dst = d1; idx = i; }
    else if (i < n1 + n2)      { src = s2; dst = d2; idx = i - n1; }
    else if (i < n1 + n2 + n3) { src = s3; dst = d3; idx = i - n1 - n2; }
    else return;
    float4 v = *(const float4*)(src + (size_t)idx * 4);
    bfx4 o = { f2bf(v.x), f2bf(v.y), f2bf(v.z), f2bf(v.w) };
    *(bfx4*)((short*)dst + (size_t)idx * 4) = o;
}

// ---------------------------------------------------------------- in_proj GEMM — EXACT R5/R7 body (measured ~90us)
__global__ __launch_bounds__(256) void gemm_in(const __hip_bfloat16* __restrict__ Abase,
                                               const __hip_bfloat16* __restrict__ Bbase, size_t bStride,
                                               __hip_bfloat16* __restrict__ Zb,
                                               __hip_bfloat16* __restrict__ Xb,
                                               float* __restrict__ DT,
                                               float* __restrict__ LA,
                                               const float* __restrict__ dtbias,
                                               const float* __restrict__ Alog,
                                               int N, int K) {
    __shared__ short As[2][32 * 64];   // 4 KB per buf
    __shared__ short Bs[2][64 * 64];   // 8 KB per buf
    __shared__ short Tr[32][136];      // transpose staging (separate, as in R5)
    int tid = threadIdx.x;
    int w = tid >> 6, lane = tid & 63;
    int q = lane >> 4, mm = lane & 15;
    int wm = w >> 1, wn = w & 1;
    int m0 = blockIdx.x * 64, n0 = blockIdx.y * 128;
    int dir = blockIdx.z;
    const short* Ag = (const short*)Abase;
    const short* Bg = (const short*)Bbase + (size_t)dir * bStride;
    int fA = dir;

    size_t aoff; int aldso;
    {
        int ln = w * 8 + (lane >> 3);
        int s  = lane & 7;
        int c  = s ^ (ln & 7);
        int row = (c < 4) ? ln : ln + 32;
        int ch  = (c < 4) ? c : (c ^ 4);
        int ar = m0 + row;
        if (fA) { int bb = ar >> 11, tt = ar & 2047; ar = (bb << 11) + (2047 - tt); }
        aoff = (size_t)ar * K + ch * 8;
        aldso = w * 1024;
    }
    size_t boff[2];
    int bldso[2];
#pragma unroll
    for (int j = 0; j < 2; j++) {
        int widx = w * 2 + j;
        int ln = widx * 8 + (lane >> 3);
        int s  = lane & 7;
        int c  = s ^ (ln & 7);
        int row = (c < 4) ? ln : ln + 64;
        int ch  = (c < 4) ? c : (c ^ 4);
        int br = n0 + row; if (br > N - 1) br = N - 1;
        boff[j] = (size_t)br * K + ch * 8;
        bldso[j] = widx * 1024;
    }

    floatx4 acc[8];
#pragma unroll
    for (int i = 0; i < 8; i++) acc[i] = (floatx4){0.f, 0.f, 0.f, 0.f};

    int niter = K / 32;
    auto stage = [&](int buf, int k0) {
        gl_lds16(Ag + aoff + k0, (char*)&As[buf][0] + aldso);
        gl_lds16(Bg + boff[0] + k0, (char*)&Bs[buf][0] + bldso[0]);
        gl_lds16(Bg + boff[1] + k0, (char*)&Bs[buf][0] + bldso[1]);
    };
    stage(0, 0);
    int slotA = (q ^ (mm & 7) ^ (wm << 2)) * 8;
    int slotB = (q ^ (mm & 7) ^ (wn << 2)) * 8;
    for (int it = 0; it < niter; it++) {
        __syncthreads();
        if (it + 1 < niter) stage((it + 1) & 1, (it + 1) * 32);
        const short* Ab = &As[it & 1][0];
        const short* Bb = &Bs[it & 1][0];
        short8 af[2], bfr[4];
#pragma unroll
        for (int mb = 0; mb < 2; mb++)
            af[mb] = *(const short8*)&Ab[(mb * 16 + mm) * 64 + slotA];
#pragma unroll
        for (int nb = 0; nb < 4; nb++)
            bfr[nb] = *(const short8*)&Bb[(nb * 16 + mm) * 64 + slotB];
#pragma unroll
        for (int mb = 0; mb < 2; mb++)
#pragma unroll
            for (int nb = 0; nb < 4; nb++)
                acc[mb * 4 + nb] = __builtin_amdgcn_mfma_f32_16x16x32_bf16(af[mb], bfr[nb], acc[mb * 4 + nb], 0, 0, 0);
    }

    __hip_bfloat16* Zb2 = Zb + (size_t)dir * 4096 * DINNER;
    __hip_bfloat16* Xb2 = Xb + (size_t)dir * 4096 * CONVDIM;

    if (n0 + 128 <= DINNER + CONVDIM) {
        short* dstBase; int ldd, c0;
        if (n0 < DINNER) { dstBase = (short*)Zb2; ldd = DINNER; c0 = n0; }
        else             { dstBase = (short*)Xb2; ldd = CONVDIM; c0 = n0 - DINNER; }
#pragma unroll
        for (int p = 0; p < 2; p++) {
            __syncthreads();
            if (wm == p) {
#pragma unroll
                for (int mb = 0; mb < 2; mb++)
#pragma unroll
                    for (int nb = 0; nb < 4; nb++)
#pragma unroll
                        for (int r = 0; r < 4; r++)
                            Tr[mb * 16 + q * 4 + r][wn * 64 + nb * 16 + mm] =
                                f2bf(acc[mb * 4 + nb][r]);
            }
            __syncthreads();
            int row = tid >> 3, c16 = (tid & 7) * 16;
            short8 v0 = *(const short8*)&Tr[row][c16];
            short8 v1 = *(const short8*)&Tr[row][c16 + 8];
            short* dp = dstBase + (size_t)(m0 + p * 32 + row) * ldd + c0 + c16;
            *(short8*)dp = v0;
            *(short8*)(dp + 8) = v1;
        }
        return;
    }

    // dt-head block: scalar path with softplus
    float* DT2 = DT + (size_t)dir * 4096 * NH;
    float* LA2 = LA + (size_t)dir * 4096 * NH;
    const float* dtb2 = dtbias + dir * NH;
    const float* Al2  = Alog + dir * NH;
#pragma unroll
    for (int mb = 0; mb < 2; mb++) {
#pragma unroll
        for (int nb = 0; nb < 4; nb++) {
            int col = n0 + wn * 64 + nb * 16 + mm;
            if (col >= N) continue;
#pragma unroll
            for (int r = 0; r < 4; r++) {
                int rr = m0 + wm * 32 + mb * 16 + q * 4 + r;
                float v = acc[mb * 4 + nb][r];
                int hh = col - (DINNER + CONVDIM);
                float raw = v + dtb2[hh];
                float dtv = (raw > 20.f) ? raw : log1pf(__expf(raw));
                float Av  = -__expf(Al2[hh]);
                DT2[(size_t)rr * NH + hh] = dtv;
                LA2[(size_t)rr * NH + hh] = dtv * Av;
            }
        }
    }
}

// ---------------------------------------------------------------- out_proj GEMM — R7 form: z = kslice (2), dirs fused
__global__ __launch_bounds__(256) void gemm_out(const __hip_bfloat16* __restrict__ Abase, size_t aStride,
                                                const __hip_bfloat16* __restrict__ Bbase, size_t bStride,
                                                float* __restrict__ C,
                                                int N, int K, int zdiv) {
    __shared__ short As[2][32 * 64];
    __shared__ short Bs[2][64 * 64];
    int tid = threadIdx.x;
    int w = tid >> 6, lane = tid & 63;
    int q = lane >> 4, mm = lane & 15;
    int wm = w >> 1, wn = w & 1;
    int m0 = blockIdx.x * 64, n0 = blockIdx.y * 128;
    int z = blockIdx.z;
    int kl   = K / zdiv;
    int kbeg = z * kl;
    int niter = kl / 32;

    int aRow, aCh, aldso;
    {
        int ln = w * 8 + (lane >> 3);
        int s  = lane & 7;
        int c  = s ^ (ln & 7);
        aRow = (c < 4) ? ln : ln + 32;
        aCh  = (c < 4) ? c : (c ^ 4);
        aldso = w * 1024;
    }
    int bRow[2], bCh[2], bldso[2];
#pragma unroll
    for (int j = 0; j < 2; j++) {
        int widx = w * 2 + j;
        int ln = widx * 8 + (lane >> 3);
        int s  = lane & 7;
        int c  = s ^ (ln & 7);
        bRow[j] = (c < 4) ? ln : ln + 64;
        bCh[j]  = (c < 4) ? c : (c ^ 4);
        bldso[j] = widx * 1024;
    }

    floatx4 acc[8];
#pragma unroll
    for (int i = 0; i < 8; i++) acc[i] = (floatx4){0.f, 0.f, 0.f, 0.f};

    int slotA = (q ^ (mm & 7) ^ (wm << 2)) * 8;
    int slotB = (q ^ (mm & 7) ^ (wn << 2)) * 8;

    for (int d = 0; d < 2; d++) {
        const short* Ag = (const short*)Abase + (size_t)d * aStride;
        const short* Bg = (const short*)Bbase + (size_t)d * bStride;
        size_t aoff;
        {
            int ar = m0 + aRow;
            if (d) { int bb = ar >> 11, tt = ar & 2047; ar = (bb << 11) + (2047 - tt); }
            aoff = (size_t)ar * K + aCh * 8;
        }
        size_t boff[2];
#pragma unroll
        for (int j = 0; j < 2; j++) {
            int br = n0 + bRow[j]; if (br > N - 1) br = N - 1;
            boff[j] = (size_t)br * K + bCh[j] * 8;
        }
        auto stage = [&](int buf, int k0) {
            gl_lds16(Ag + aoff + kbeg + k0, (char*)&As[buf][0] + aldso);
            gl_lds16(Bg + boff[0] + kbeg + k0, (char*)&Bs[buf][0] + bldso[0]);
            gl_lds16(Bg + boff[1] + kbeg + k0, (char*)&Bs[buf][0] + bldso[1]);
        };
        stage(0, 0);
        for (int it = 0; it < niter; it++) {
            __syncthreads();
            if (it + 1 < niter) stage((it + 1) & 1, (it + 1) * 32);
            const short* Ab = &As[it & 1][0];
            const short* Bb = &Bs[it & 1][0];
            short8 af[2], bfr[4];
#pragma unroll
            for (int mb = 0; mb < 2; mb++)
                af[mb] = *(const short8*)&Ab[(mb * 16 + mm) * 64 + slotA];
#pragma unroll
            for (int nb = 0; nb < 4; nb++)
                bfr[nb] = *(const short8*)&Bb[(nb * 16 + mm) * 64 + slotB];
#pragma unroll
            for (int mb = 0; mb < 2; mb++)
#pragma unroll
                for (int nb = 0; nb < 4; nb++)
                    acc[mb * 4 + nb] = __builtin_amdgcn_mfma_f32_16x16x32_bf16(af[mb], bfr[nb], acc[mb * 4 + nb], 0, 0, 0);
        }
    }

    float* Cz = C + (size_t)z * 4096 * 768;
#pragma unroll
    for (int mb = 0; mb < 2; mb++)
#pragma unroll
        for (int nb = 0; nb < 4; nb++) {
            int col = n0 + wn * 64 + nb * 16 + mm;
#pragma unroll
            for (int r = 0; r < 4; r++) {
                int rr = m0 + wm * 32 + mb * 16 + q * 4 + r;
                Cz[(size_t)rr * 768 + col] = acc[mb * 4 + nb][r];
            }
        }
}

// ---------------------------------------------------------------- out_proj reduce: out = P0 + P1 (dirs pre-summed)
__global__ __launch_bounds__(256) void reduce2_kernel(const float* __restrict__ P, float* __restrict__ out) {
    int idx = blockIdx.x * 256 + threadIdx.x;   // 4096*192 float4 slots
    const size_t sl = (size_t)4096 * 192;
    const float4* P4 = (const float4*)P;
    float4 a = P4[idx];
    float4 b = P4[sl + idx];
    float4 o = { a.x + b.x, a.y + b.y, a.z + b.z, a.w + b.w };
    ((float4*)out)[idx] = o;
}

// ---------------------------------------------------------------- conv (depthwise K=4) + silu — 2x parallelism (8 t/thread)
__global__ __launch_bounds__(256) void conv_kernel(const __hip_bfloat16* __restrict__ Xb,
                                                   const float* __restrict__ conv_w,
                                                   const float* __restrict__ conv_b,
                                                   __hip_bfloat16* __restrict__ xh,
                                                   __hip_bfloat16* __restrict__ Bm,
                                                   __hip_bfloat16* __restrict__ Cm) {
    int db  = blockIdx.x >> 8;
    int dir = db >> 1;
    int t0  = (blockIdx.x & 255) * 8;
    int c8  = threadIdx.x * 8;
    if (c8 >= CONVDIM) return;

    float wk[4][8], bs[8];
#pragma unroll
    for (int j = 0; j < 8; j++) {
        bs[j] = conv_b[dir * CONVDIM + c8 + j];
#pragma unroll
        for (int k = 0; k < 4; k++) wk[k][j] = conv_w[((size_t)dir * CONVDIM + c8 + j) * 4 + k];
    }

    const short* xrow = (const short*)Xb + (size_t)db * SEQ * CONVDIM + c8;
    short8 win[4];
    const short8 zer = {0, 0, 0, 0, 0, 0, 0, 0};
#pragma unroll
    for (int k = 0; k < 3; k++) {
        int ts = t0 - 3 + k;
        win[k] = (ts >= 0) ? *(const short8*)(xrow + (size_t)ts * CONVDIM) : zer;
    }

    for (int tt = 0; tt < 8; tt++) {
        int t = t0 + tt;
        win[3] = *(const short8*)(xrow + (size_t)t * CONVDIM);
        short8 outv;
#pragma unroll
        for (int j = 0; j < 8; j++) {
            float acc = bs[j];
#pragma unroll
            for (int k = 0; k < 4; k++) acc += wk[k][j] * bf2f(win[k][j]);
            float sv = acc / (1.f + __expf(-acc));
            outv[j] = f2bf(sv);
        }
        if (c8 < DINNER)
            *(short8*)((short*)xh + (size_t)(db * SEQ + t) * DINNER + c8) = outv;
        else if (c8 < DINNER + DSTATE)
            *(short8*)((short*)Bm + (size_t)(db * SEQ + t) * DSTATE + (c8 - DINNER)) = outv;
        else
            *(short8*)((short*)Cm + (size_t)(db * SEQ + t) * DSTATE + (c8 - DINNER - DSTATE)) = outv;
        win[0] = win[1]; win[1] = win[2]; win[2] = win[3];
    }
}

// ---------------------------------------------------------------- SSD pass 1
__global__ __launch_bounds__(256) void ssd1_kernel(const __hip_bfloat16* __restrict__ XH,
                                                   const __hip_bfloat16* __restrict__ BMh,
                                                   const float* __restrict__ DT,
                                                   const float* __restrict__ LA,
                                                   short* __restrict__ SS,
                                                   float* __restrict__ CUM) {
    int blk = blockIdx.x;
    int ck = blk & 31;
    int dbh = blk >> 5;
    int hh = dbh % NH, db = dbh / NH;
    int base_row = db * SEQ + ck * QCH;

    __shared__ float cum_s[QCH], dt_s[QCH];
    __shared__ short Xt[64][72];
    __shared__ short Bt[128][72];

    int tid = threadIdx.x;
    int lane = tid & 63, w = tid >> 6;
    int q = lane >> 4, mm = lane & 15;

    if (tid < QCH) {
        float la  = LA[(size_t)(base_row + tid) * NH + hh];
        float dtv = DT[(size_t)(base_row + tid) * NH + hh];
        float cs = la;
#pragma unroll
        for (int d = 1; d < 64; d <<= 1) {
            float u = __shfl_up(cs, d);
            if (tid >= d) cs += u;
        }
        cum_s[tid] = cs;
        dt_s[tid] = dtv;
        CUM[(size_t)dbh * SEQ + ck * QCH + tid] = cs;
    }
    __syncthreads();
    float cumL = cum_s[QCH - 1];

    {
        int s2 = (tid & 31) * 2, pb = tid >> 5;
        float f0 = dt_s[s2]     * __expf(cumL - cum_s[s2]);
        float f1 = dt_s[s2 + 1] * __expf(cumL - cum_s[s2 + 1]);
        const short* r0 = (const short*)XH + (size_t)(base_row + s2) * DINNER + hh * 64 + pb * 8;
        const short* r1 = r0 + DINNER;
        short8 x0 = *(const short8*)r0;
        short8 x1 = *(const short8*)r1;
#pragma unroll
        for (int j = 0; j < 8; j++) {
            unsigned lo = (unsigned short)f2bf(f0 * bf2f(x0[j]));
            unsigned hi = (unsigned short)f2bf(f1 * bf2f(x1[j]));
            *(unsigned*)&Xt[pb * 8 + j][s2] = lo | (hi << 16);
        }
    }
    {
        int s2 = (tid & 31) * 2, nb = tid >> 5;
        const short* r0 = (const short*)BMh + (size_t)(base_row + s2) * DSTATE + nb * 16;
        const short* r1 = r0 + DSTATE;
        short8 b0a = *(const short8*)r0,  b0b = *(const short8*)(r0 + 8);
        short8 b1a = *(const short8*)r1,  b1b = *(const short8*)(r1 + 8);
#pragma unroll
        for (int j = 0; j < 8; j++) {
            *(unsigned*)&Bt[nb * 16 + j][s2] =
                (unsigned)(unsigned short)b0a[j] | ((unsigned)(unsigned short)b1a[j] << 16);
            *(unsigned*)&Bt[nb * 16 + 8 + j][s2] =
                (unsigned)(unsigned short)b0b[j] | ((unsigned)(unsigned short)b1b[j] << 16);
        }
    }
    __syncthreads();

    floatx4 acc[8];
#pragma unroll
    for (int i = 0; i < 8; i++) acc[i] = (floatx4){0.f, 0.f, 0.f, 0.f};
#pragma unroll
    for (int kk = 0; kk < 2; kk++) {
        short8 a = *(const short8*)&Xt[w * 16 + mm][kk * 32 + q * 8];
#pragma unroll
        for (int cb = 0; cb < 8; cb++) {
            short8 b = *(const short8*)&Bt[cb * 16 + mm][kk * 32 + q * 8];
            acc[cb] = __builtin_amdgcn_mfma_f32_16x16x32_bf16(a, b, acc[cb], 0, 0, 0);
        }
    }
    short* Sp = SS + (size_t)blk * 8192;
#pragma unroll
    for (int cb = 0; cb < 8; cb++)
#pragma unroll
        for (int r = 0; r < 4; r++)
            Sp[(w * 16 + q * 4 + r) * DSTATE + cb * 16 + mm] = f2bf(acc[cb][r]);
}

// ---------------------------------------------------------------- SSD pass 2: IN-PLACE inter-chunk scan (R12 form)
__global__ __launch_bounds__(128) void ssd2_kernel(short* __restrict__ SS,
                                                   const float* __restrict__ CUM) {
    int blk = blockIdx.x;
    int dbh = blk >> 3, part = blk & 7;
    int off = part * 1024 + threadIdx.x * 8;
    size_t base = (size_t)dbh * NCH * 8192 + off;
    float h[8];
#pragma unroll
    for (int j = 0; j < 8; j++) h[j] = 0.f;
    for (int c = 0; c < NCH; c++) {
        float W = __expf(CUM[(size_t)dbh * SEQ + c * QCH + QCH - 1]);
        size_t p = base + (size_t)c * 8192;
        short8 s = *(const short8*)(SS + p);
        short8 o;
#pragma unroll
        for (int j = 0; j < 8; j++) o[j] = f2bf(h[j]);
        *(short8*)(SS + p) = o;
#pragma unroll
        for (int j = 0; j < 8; j++) h[j] = fmaf(h[j], W, bf2f(s[j]));
    }
}

// ---------------------------------------------------------------- SSD pass 3 (+ fused D*xh; single Cg read via LDS)
__global__ __launch_bounds__(256) void ssd3_kernel(const __hip_bfloat16* __restrict__ XH,
                                                   const __hip_bfloat16* __restrict__ BMh,
                                                   const __hip_bfloat16* __restrict__ CMh,
                                                   const float* __restrict__ DT,
                                                   const float* __restrict__ CUM,
                                                   const short* __restrict__ Hprev,
                                                   const float* __restrict__ Dp,
                                                   __hip_bfloat16* __restrict__ Yb) {
    int blk = blockIdx.x;
    int ck = blk & 31;
    int dbh = blk >> 5;
    int hh = dbh % NH, db = dbh / NH;
    int base_row = db * SEQ + ck * QCH;
    float Dv = Dp[(db >> 1) * NH + hh];   // dir = db>>1

    __shared__ float cum_s[QCH], dt_s[QCH];
    __shared__ short Ct[64][136];
    __shared__ short G[64][72];
    __shared__ short Xt[64][72];

    int tid = threadIdx.x;
    int lane = tid & 63, w = tid >> 6;
    int q = lane >> 4, mm = lane & 15;

    if (tid < QCH) {
        cum_s[tid] = CUM[(size_t)dbh * SEQ + ck * QCH + tid];
        dt_s[tid]  = DT[(size_t)(base_row + tid) * NH + hh];
    }

    const short* Cg = (const short*)CMh + (size_t)base_row * DSTATE;
    const short* Bg = (const short*)BMh + (size_t)base_row * DSTATE;

    // stage Cg RAW into Ct: thread (t = tid&63, nb4 = tid>>6) covers cols nb4*32..+31
    {
        int t = tid & 63, nb4 = tid >> 6;
        const short* src = Cg + (size_t)t * DSTATE + nb4 * 32;
#pragma unroll
        for (int u = 0; u < 2; u++) {
            *(short8*)&Ct[t][nb4 * 32 + u * 16]     = *(const short8*)(src + u * 16);
            *(short8*)&Ct[t][nb4 * 32 + u * 16 + 8] = *(const short8*)(src + u * 16 + 8);
        }
    }
    // Xt staging (independent of Ct)
    {
        int s2 = (tid & 31) * 2, pb = tid >> 5;
        const short* r0 = (const short*)XH + (size_t)(base_row + s2) * DINNER + hh * 64 + pb * 8;
        const short* r1 = r0 + DINNER;
        short8 x0 = *(const short8*)r0;
        short8 x1 = *(const short8*)r1;
#pragma unroll
        for (int j = 0; j < 8; j++) {
            *(unsigned*)&Xt[pb * 8 + j][s2] =
                (unsigned)(unsigned short)x0[j] | ((unsigned)(unsigned short)x1[j] << 16);
        }
    }
    __syncthreads();

    // P = C . B^T : A-fragments from Ct (LDS), B from global
    floatx4 P[4];
#pragma unroll
    for (int i = 0; i < 4; i++) P[i] = (floatx4){0.f, 0.f, 0.f, 0.f};
#pragma unroll
    for (int kk = 0; kk < 4; kk++) {
        short8 a = *(const short8*)&Ct[w * 16 + mm][kk * 32 + q * 8];
#pragma unroll
        for (int cb = 0; cb < 4; cb++) {
            short8 b = *(const short8*)(Bg + (size_t)(cb * 16 + mm) * DSTATE + kk * 32 + q * 8);
            P[cb] = __builtin_amdgcn_mfma_f32_16x16x32_bf16(a, b, P[cb], 0, 0, 0);
        }
    }
    __syncthreads();   // all Ct reads for P done; safe to overwrite

    // weight Ct in place: Ct[t][s] *= exp(cum[t]); G from P
    {
        int t = tid & 63, nb4 = tid >> 6;
        float wt = __expf(cum_s[t]);
#pragma unroll
        for (int u = 0; u < 4; u++) {
            short8 v = *(const short8*)&Ct[t][nb4 * 32 + u * 8];
            short8 o;
#pragma unroll
            for (int j = 0; j < 8; j++) o[j] = f2bf(wt * bf2f(v[j]));
            *(short8*)&Ct[t][nb4 * 32 + u * 8] = o;
        }
    }
#pragma unroll
    for (int cb = 0; cb < 4; cb++) {
#pragma unroll
        for (int r = 0; r < 4; r++) {
            int t = w * 16 + q * 4 + r;
            int s = cb * 16 + mm;
            float g = (s <= t) ? P[cb][r] * __expf(cum_s[t] - cum_s[s]) * dt_s[s] : 0.f;
            G[t][s] = f2bf(g);
        }
    }
    __syncthreads();

    floatx4 Y[4];
#pragma unroll
    for (int i = 0; i < 4; i++) Y[i] = (floatx4){0.f, 0.f, 0.f, 0.f};
#pragma unroll
    for (int kk = 0; kk < 2; kk++) {
        short8 a = *(const short8*)&G[w * 16 + mm][kk * 32 + q * 8];
#pragma unroll
        for (int cb = 0; cb < 4; cb++) {
            short8 b = *(const short8*)&Xt[cb * 16 + mm][kk * 32 + q * 8];
            Y[cb] = __builtin_amdgcn_mfma_f32_16x16x32_bf16(a, b, Y[cb], 0, 0, 0);
        }
    }
    const short* Hc = Hprev + (size_t)blk * 8192;
#pragma unroll
    for (int kk = 0; kk < 4; kk++) {
        short8 a = *(const short8*)&Ct[w * 16 + mm][kk * 32 + q * 8];
#pragma unroll
        for (int cb = 0; cb < 4; cb++) {
            short8 b = *(const short8*)(Hc + (size_t)(cb * 16 + mm) * DSTATE + kk * 32 + q * 8);
            Y[cb] = __builtin_amdgcn_mfma_f32_16x16x32_bf16(a, b, Y[cb], 0, 0, 0);
        }
    }
    // fused D*xh: Xt[p][t] = xh[base_row+t][hh*64+p], p = cb*16+mm, t = w*16+q*4+r
#pragma unroll
    for (int cb = 0; cb < 4; cb++)
#pragma unroll
        for (int r = 0; r < 4; r++) {
            int t = w * 16 + q * 4 + r;
            float yv = Y[cb][r] + Dv * bf2f(Xt[cb * 16 + mm][t]);
            Yb[(size_t)(base_row + t) * DINNER + hh * 64 + cb * 16 + mm] = __float2bfloat16(yv);
        }
}

// ---------------------------------------------------------------- gating + RMSNorm (192 thr x 8 ch; xh pre-folded)
__global__ __launch_bounds__(192) void gate_kernel(const __hip_bfloat16* __restrict__ Yb,
                                                   const __hip_bfloat16* __restrict__ Zb,
                                                   const float* __restrict__ norm_w,
                                                   __hip_bfloat16* __restrict__ A2) {
    int row = blockIdx.x;
    int dir = row >> 12;
    int c8 = threadIdx.x * 8;
    const short* yr = (const short*)Yb + (size_t)row * DINNER + c8;
    const short* zr = (const short*)Zb + (size_t)row * DINNER + c8;

    short8 y8 = *(const short8*)yr;
    short8 z8 = *(const short8*)zr;

    float vals[8];
    float ss = 0.f;
#pragma unroll
    for (int j = 0; j < 8; j++) {
        float v = bf2f(y8[j]);
        float z = bf2f(z8[j]);
        v *= z / (1.f + __expf(-z));
        vals[j] = v;
        ss += v * v;
    }
#pragma unroll
    for (int off = 32; off; off >>= 1) ss += __shfl_down(ss, off);
    __shared__ float ls[3];
    if ((threadIdx.x & 63) == 0) ls[threadIdx.x >> 6] = ss;
    __syncthreads();
    float tot = ls[0] + ls[1] + ls[2];
    float scale = rsqrtf(tot / (float)DINNER + 1e-5f);

    const float* nw = norm_w + dir * DINNER + c8;
    short8 o;
#pragma unroll
    for (int j = 0; j < 8; j++) o[j] = f2bf(vals[j] * scale * nw[j]);
    *(short8*)((short*)A2 + (size_t)row * DINNER + c8) = o;
}

// ---------------------------------------------------------------- launch
extern "C" void kernel_launch(void* const* d_in, const int* in_sizes, int n_in,
                              void* d_out, int out_size, void* d_ws, size_t ws_size,
                              hipStream_t stream) {
    const float* x        = (const float*)d_in[0];
    const float* in_w     = (const float*)d_in[1];
    const float* conv_w   = (const float*)d_in[2];
    const float* conv_b   = (const float*)d_in[3];
    const float* dt_bias  = (const float*)d_in[4];
    const float* A_log    = (const float*)d_in[5];
    const float* Dp       = (const float*)d_in[6];
    const float* norm_w   = (const float*)d_in[7];
    const float* out_w    = (const float*)d_in[8];
    float* out = (float*)d_out;

    const size_t szW2 = (size_t)2 * DMODEL * DINNER * 2;
    const size_t szZ  = (size_t)8192 * DINNER * 2;
    const size_t szXH = (size_t)8192 * DINNER * 2;
    const size_t szBM = (size_t)8192 * DSTATE * 2;
    const size_t szCM = szBM;
    const size_t szDT = (size_t)8192 * NH * 4;
    const size_t szLA = szDT;
    const size_t szA1 = (size_t)4096 * DMODEL * 2;     // unflipped, shared by both dirs
    const size_t szW1 = (size_t)2 * NPROJ * DMODEL * 2;
    const size_t szXB = (size_t)8192 * CONVDIM * 2;
    const size_t szYb = (size_t)8192 * DINNER * 2;
    const size_t szSS = (size_t)96 * NCH * 8192 * 2;   // 50.33 MB (scanned in-place by ssd2)
    const size_t szCp = (size_t)2 * 4096 * 768 * 4;    // 25.2 MB (2 dir-summed K-slices)
    const size_t szRa = szA1 + szW1 + szXB;
    size_t szR = szRa;
    if (szR < szYb) szR = szYb;
    if (szR < szCp) szR = szCp;
    const size_t szCU = (size_t)96 * SEQ * 4;

    char* ws = (char*)d_ws;
    size_t off = 0;
    auto alloc = [&](size_t bytes) { char* p = ws + off; off += (bytes + 255) & ~(size_t)255; return p; };

    __hip_bfloat16* W2 = (__hip_bfloat16*)alloc(szW2);
    __hip_bfloat16* Z  = (__hip_bfloat16*)alloc(szZ);
    __hip_bfloat16* XH = (__hip_bfloat16*)alloc(szXH);
    __hip_bfloat16* BM = (__hip_bfloat16*)alloc(szBM);
    __hip_bfloat16* CM = (__hip_bfloat16*)alloc(szCM);
    float* DT = (float*)alloc(szDT);
    float* LA = (float*)alloc(szLA);
    char*  R  = (char*)alloc(szR);
    __hip_bfloat16* A1  = (__hip_bfloat16*)R;
    __hip_bfloat16* W1  = (__hip_bfloat16*)(R + szA1);
    __hip_bfloat16* XBC = (__hip_bfloat16*)(R + szA1 + szW1);
    __hip_bfloat16* Yb = (__hip_bfloat16*)R;
    float* Cpart = (float*)R;     // dead after gate_kernel

    short* SS = (short*)alloc(szSS);   // own buffer: written by ssd1, scanned in-place, read by ssd3
    float* CU = (float*)alloc(szCU);
    if (off > ws_size) return;   // clean fail instead of OOB crash

    // 1. fused converts: weights + x (A1 rows = b*SEQ+t, unflipped)
    int n1 = 2 * NPROJ * DMODEL / 4;
    int n2 = 2 * DMODEL * DINNER / 4;
    int n3 = 4096 * DMODEL / 4;
    cvt3_kernel<<<(n1 + n2 + n3 + 255) / 256, 256, 0, stream>>>(in_w, W1, n1, out_w, W2, n2, x, A1, n3);

    // 2. in_proj GEMM: exact R5/R7 kernel (~90us), z = dir, dir1 flips A rows in-gather
    {
        dim3 grid(4096 / 64, (NPROJ + 127) / 128, 2);
        gemm_in<<<grid, 256, 0, stream>>>(A1,
                                          W1, (size_t)NPROJ * DMODEL,
                                          Z, XBC, DT, LA, dt_bias, A_log,
                                          NPROJ, DMODEL);
    }

    // 3. conv + silu (2x parallelism: 1024 blocks, 8 timesteps/thread)
    conv_kernel<<<4 * 256, 256, 0, stream>>>(XBC, conv_w, conv_b, XH, BM, CM);

    // 4. SSD chunked scan (3-pass); ssd2 scans SS in place; ssd3 single-Cg-read + D*xh fold
    ssd1_kernel<<<4 * NH * NCH, 256, 0, stream>>>(XH, BM, DT, LA, SS, CU);
    ssd2_kernel<<<96 * 8, 128, 0, stream>>>(SS, CU);
    ssd3_kernel<<<4 * NH * NCH, 256, 0, stream>>>(XH, BM, CM, DT, CU, SS, Dp, Yb);

    // 5. gating + RMSNorm (xh pre-folded; A2 == Z, in-place)
    gate_kernel<<<2 * 4096, 192, 0, stream>>>(Yb, Z, norm_w, Z);

    // 6. out_proj: R7 form — z = kslice (2), dirs fused in-kernel, then reduce2
    {
        dim3 grid(4096 / 64, DMODEL / 128, 2);
        gemm_out<<<grid, 256, 0, stream>>>(Z, (size_t)4096 * DINNER,
                                           W2, (size_t)DMODEL * DINNER,
                                           Cpart,
                                           DMODEL, DINNER, 2);
    }
    reduce2_kernel<<<4096 * 192 / 256, 256, 0, stream>>>(Cpart, out);
}